// Round 7
// baseline (977.242 us; speedup 1.0000x reference)
//
#include <hip/hip_runtime.h>
#include <math.h>

typedef __attribute__((ext_vector_type(8))) short bf16x8;
typedef __attribute__((ext_vector_type(4))) float f32x4;
typedef __attribute__((ext_vector_type(4))) float float4v;

__device__ __forceinline__ short f2bf(float v) {
  union { float f; unsigned u; } x; x.f = v;
  unsigned r = x.u + 0x7fffu + ((x.u >> 16) & 1u);
  return (short)(r >> 16);
}

__device__ __forceinline__ float bf2f(unsigned short u) {
  union { unsigned u; float f; } x; x.u = ((unsigned)u) << 16;
  return x.f;
}

__device__ __forceinline__ void gld_lds16(const void* g, void* l) {
  __builtin_amdgcn_global_load_lds((const __attribute__((address_space(1))) void*)g,
                                   (__attribute__((address_space(3))) void*)l, 16, 0, 0);
}

// ---------------- transpose fp32 [R,C] -> bf16 [C,R], batched over z ----------------
__global__ __launch_bounds__(256) void transpose_bf(const float* __restrict__ src,
                                                    short* __restrict__ dst,
                                                    int R, int C, size_t sStride, size_t dStride) {
  __shared__ float t[32][33];
  src += blockIdx.z * sStride;
  dst += blockIdx.z * dStride;
  int tx = threadIdx.x & 31, ty = threadIdx.x >> 5;  // 32 x 8
  int c0 = blockIdx.x * 32, r0 = blockIdx.y * 32;
#pragma unroll
  for (int i = 0; i < 4; i++)
    t[ty + i * 8][tx] = src[(size_t)(r0 + ty + i * 8) * C + c0 + tx];
  __syncthreads();
#pragma unroll
  for (int i = 0; i < 4; i++)
    dst[(size_t)(c0 + ty + i * 8) * R + r0 + tx] = f2bf(t[tx][ty + i * 8]);
}

// ---------------- transpose Wq/Wk/Wv [512,512] fp32 -> qkvt bf16, one dispatch ----------------
__global__ __launch_bounds__(256) void transpose_qkv(const float* __restrict__ Wq,
                                                     const float* __restrict__ Wk,
                                                     const float* __restrict__ Wv,
                                                     short* __restrict__ qkvt) {
  __shared__ float t[32][33];
  const int z = blockIdx.z;           // 0..17
  const int which = z / 6, l = z % 6;
  const float* src = (which == 0 ? Wq : which == 1 ? Wk : Wv) + (size_t)l * 262144;
  short* dst = qkvt + (size_t)l * 786432 + (size_t)which * 262144;
  int tx = threadIdx.x & 31, ty = threadIdx.x >> 5;
  int c0 = blockIdx.x * 32, r0 = blockIdx.y * 32;
#pragma unroll
  for (int i = 0; i < 4; i++)
    t[ty + i * 8][tx] = src[(size_t)(r0 + ty + i * 8) * 512 + c0 + tx];
  __syncthreads();
#pragma unroll
  for (int i = 0; i < 4; i++)
    dst[(size_t)(c0 + ty + i * 8) * 512 + r0 + tx] = f2bf(t[tx][ty + i * 8]);
}

// ---------------- embed: h = x @ W_in + b_in + pe; also bf16 copy ----------------
__global__ void embed_kernel(const float* __restrict__ x, const float* __restrict__ W_in,
                             const float* __restrict__ b_in, const float* __restrict__ pe,
                             float* __restrict__ h, short* __restrict__ hbf) {
  int col = (blockIdx.x & 1) * 256 + threadIdx.x;
  int row = blockIdx.x >> 1;
  int s = row & 511;
  float a = b_in[col] + pe[s * 512 + col];
  const float* xr = x + (size_t)row * 32;
#pragma unroll
  for (int k = 0; k < 32; k++) a += xr[k] * W_in[k * 512 + col];
  h[(size_t)row * 512 + col] = a;
  hbf[(size_t)row * 512 + col] = f2bf(a);
}

// ---------------- bf16 GEMM: A[M,K] x Bt[N,K]^T -> C[M,N] ----------------
// EPI: 0 f32; 1 f32+bias; 2 bf16+bias+relu; 3 bf16; 4 bf16+bias
// BK=32: LDS row stride 64B -> only 2-way bank aliasing on ds_read_b128 (free per m136).
// BK=64 measured 4.7M conflicts/dispatch (32-way, 128B stride) -> do not raise BK.
template <int EPI, int BM, int BN, int BK>
__global__ __launch_bounds__(256) void gemm_bt(const short* __restrict__ A,
                                               const short* __restrict__ Bt,
                                               float* __restrict__ Cf, short* __restrict__ Cb,
                                               const float* __restrict__ bias,
                                               int M, int N, int K) {
  __shared__ short As[BM * BK];
  __shared__ short Bs[BN * BK];
  const int tid = threadIdx.x;
  const int wid = tid >> 6;
  const int lane = tid & 63;
  const int m0 = blockIdx.y * BM;
  const int n0 = blockIdx.x * BN;
  constexpr int WR = BM / 2, WC = BN / 2, FI = WR / 16, FJ = WC / 16, KK = BK / 32;
  const int wr = (wid >> 1) * WR;
  const int wc = (wid & 1) * WC;

  f32x4 acc[FI][FJ];
#pragma unroll
  for (int i = 0; i < FI; i++)
#pragma unroll
    for (int j = 0; j < FJ; j++)
#pragma unroll
      for (int q = 0; q < 4; q++) acc[i][j][q] = 0.0f;

  const short* aBase = A + (size_t)m0 * K;
  const short* bBase = Bt + (size_t)n0 * K;
  constexpr int RPC = 512 / BK;        // rows staged per gld_lds call (1024B)
  constexpr int CA = BM / RPC;         // calls for A tile
  constexpr int CT = (BM + BN) / RPC;  // total calls
  const int rowL = lane / (64 / RPC);        // lane's row within a call
  const int colE = (lane % (64 / RPC)) * 8;  // lane's 16B slot (in shorts)
  const int kg = (lane >> 4) * 8;
  const int r16 = lane & 15;

  for (int kt = 0; kt < K; kt += BK) {
    __syncthreads();
#pragma unroll
    for (int c = 0; c < CT / 4; ++c) {
      int s = c * 4 + wid;
      if (s < CA)
        gld_lds16(aBase + (size_t)(s * RPC + rowL) * K + kt + colE, As + s * 512);
      else
        gld_lds16(bBase + (size_t)((s - CA) * RPC + rowL) * K + kt + colE, Bs + (s - CA) * 512);
    }
    __syncthreads();
    bf16x8 af[FI][KK], bfr[FJ][KK];
#pragma unroll
    for (int i = 0; i < FI; i++)
#pragma unroll
      for (int kk = 0; kk < KK; kk++)
        af[i][kk] = *(const bf16x8*)&As[(wr + i * 16 + r16) * BK + kk * 32 + kg];
#pragma unroll
    for (int j = 0; j < FJ; j++)
#pragma unroll
      for (int kk = 0; kk < KK; kk++)
        bfr[j][kk] = *(const bf16x8*)&Bs[(wc + j * 16 + r16) * BK + kk * 32 + kg];
#pragma unroll
    for (int kk = 0; kk < KK; kk++)
#pragma unroll
      for (int i = 0; i < FI; i++)
#pragma unroll
        for (int j = 0; j < FJ; j++)
          acc[i][j] = __builtin_amdgcn_mfma_f32_16x16x32_bf16(af[i][kk], bfr[j][kk], acc[i][j], 0, 0, 0);
  }

  const int col16 = lane & 15;
  const int rowg = (lane >> 4) * 4;
#pragma unroll
  for (int i = 0; i < FI; i++) {
    int row = m0 + wr + i * 16 + rowg;
#pragma unroll
    for (int j = 0; j < FJ; j++) {
      int col = n0 + wc + j * 16 + col16;
      float bv = (EPI == 1 || EPI == 2 || EPI == 4) ? bias[col] : 0.0f;
#pragma unroll
      for (int q = 0; q < 4; q++) {
        float v = acc[i][j][q] + bv;
        if (EPI == 2) {
          v = fmaxf(v, 0.0f);
          Cb[(size_t)(row + q) * N + col] = f2bf(v);
        } else if (EPI == 3 || EPI == 4) {
          Cb[(size_t)(row + q) * N + col] = f2bf(v);
        } else {
          Cf[(size_t)(row + q) * N + col] = v;
        }
      }
    }
  }
}

// ---------------- fully fused attention: per (b, 16-query tile), loops heads ----------------
// No global P: head-sum kept in registers (same thread owns same (q,t) across h),
// KL computed in-kernel. Each wave owns a 128-wide t-quarter; P staged in a
// wave-PRIVATE swizzled LDS strip (write->read same wave: no barrier needed).
template <int FIRST>
__global__ __launch_bounds__(256) void attn_fused(const short* __restrict__ qkvh,
                                                  const short* __restrict__ Vt,
                                                  short* __restrict__ ctxb,
                                                  float* __restrict__ assoc) {
  __shared__ short Pl[4][2048];      // 4 strips of 16q x 128t bf16 (swizzled), 16 KB
  __shared__ float red0[4][16];      // cross-wave softmax max
  __shared__ float red1[4][16];      // cross-wave softmax sum
  __shared__ float part[4][16][64];  // PV partials per wave, 16 KB
  __shared__ float klred[4][16];

  const int tid = threadIdx.x;
  const int wid = tid >> 6, lane = tid & 63;
  const int r16 = lane & 15, g = lane >> 4;
  const int b = blockIdx.x;          // b on x: same-b blocks share K/V in one XCD's L2
  const int q0 = blockIdx.y * 16;
  const size_t rowQ = (size_t)(b * 512 + q0 + r16) * 1536;
  const short* kbase = qkvh + (size_t)(b * 512 + wid * 128) * 1536 + 512;

  float hs[8][4];
#pragma unroll
  for (int t = 0; t < 8; t++)
#pragma unroll
    for (int r = 0; r < 4; r++) hs[t][r] = 0.f;

  for (int h = 0; h < 8; ++h) {
    // ---- QK^T on wave's t-quarter: acc[tt] rows q=g*4+r, col t=wid*128+tt*16+r16 ----
    const short* qp = qkvh + rowQ + h * 64 + g * 8;
    bf16x8 qa0 = *(const bf16x8*)qp;
    bf16x8 qa1 = *(const bf16x8*)(qp + 32);
    f32x4 acc[8];
#pragma unroll
    for (int tt = 0; tt < 8; ++tt) {
      const short* kp = kbase + (size_t)(tt * 16 + r16) * 1536 + h * 64 + g * 8;
      bf16x8 kb0 = *(const bf16x8*)kp;
      bf16x8 kb1 = *(const bf16x8*)(kp + 32);
      f32x4 c = {0.f, 0.f, 0.f, 0.f};
      c = __builtin_amdgcn_mfma_f32_16x16x32_bf16(qa0, kb0, c, 0, 0, 0);
      c = __builtin_amdgcn_mfma_f32_16x16x32_bf16(qa1, kb1, c, 0, 0, 0);
      acc[tt] = c;
    }
    // ---- softmax: local max -> 16-lane reduce -> cross-wave via LDS ----
    float mx[4] = {-1e30f, -1e30f, -1e30f, -1e30f};
#pragma unroll
    for (int tt = 0; tt < 8; ++tt)
#pragma unroll
      for (int r = 0; r < 4; ++r) mx[r] = fmaxf(mx[r], acc[tt][r]);
#pragma unroll
    for (int r = 0; r < 4; ++r)
#pragma unroll
      for (int m = 8; m; m >>= 1) mx[r] = fmaxf(mx[r], __shfl_xor(mx[r], m, 16));
    if (r16 == 0) {
#pragma unroll
      for (int r = 0; r < 4; ++r) red0[wid][g * 4 + r] = mx[r];
    }
    __syncthreads();
#pragma unroll
    for (int r = 0; r < 4; ++r) {
      int q = g * 4 + r;
      mx[r] = fmaxf(fmaxf(red0[0][q], red0[1][q]), fmaxf(red0[2][q], red0[3][q]));
    }
    float sum[4] = {0.f, 0.f, 0.f, 0.f};
#pragma unroll
    for (int tt = 0; tt < 8; ++tt)
#pragma unroll
      for (int r = 0; r < 4; ++r) {
        float e = __expf((acc[tt][r] - mx[r]) * 0.125f);
        acc[tt][r] = e;
        sum[r] += e;
      }
#pragma unroll
    for (int r = 0; r < 4; ++r)
#pragma unroll
      for (int m = 8; m; m >>= 1) sum[r] += __shfl_xor(sum[r], m, 16);
    if (r16 == 0) {
#pragma unroll
      for (int r = 0; r < 4; ++r) red1[wid][g * 4 + r] = sum[r];
    }
    __syncthreads();
    float inv[4];
#pragma unroll
    for (int r = 0; r < 4; ++r) {
      int q = g * 4 + r;
      inv[r] = 1.0f / (red1[0][q] + red1[1][q] + red1[2][q] + red1[3][q]);
    }
    // ---- P -> own LDS strip (XOR swizzle byte^=(q&7)<<4) + fp32 head-sum ----
    char* plc = (char*)Pl[wid];
#pragma unroll
    for (int r = 0; r < 4; ++r) {
      int q = g * 4 + r;
      int swz = (q & 7) << 4;
#pragma unroll
      for (int tt = 0; tt < 8; ++tt) {
        float pv = acc[tt][r] * inv[r];
        hs[tt][r] += pv;
        *(short*)(plc + q * 256 + (((tt * 16 + r16) * 2) ^ swz)) = f2bf(pv);
      }
    }
    // ---- PV on own strip (wave-private; lgkmcnt ordering is automatic) ----
    f32x4 pacc[4];
#pragma unroll
    for (int j = 0; j < 4; ++j)
#pragma unroll
      for (int q = 0; q < 4; ++q) pacc[j][q] = 0.f;
    const short* vb = Vt + (size_t)(b * 8 + h) * 64 * 512 + wid * 128;
    const int rswz = (r16 & 7) << 4;
#pragma unroll
    for (int m = 0; m < 4; ++m) {
      bf16x8 af = *(const bf16x8*)(plc + r16 * 256 + (((m * 32 + g * 8) * 2) ^ rswz));
#pragma unroll
      for (int j = 0; j < 4; ++j) {
        bf16x8 bfr = *(const bf16x8*)&vb[(size_t)(j * 16 + r16) * 512 + m * 32 + g * 8];
        pacc[j] = __builtin_amdgcn_mfma_f32_16x16x32_bf16(af, bfr, pacc[j], 0, 0, 0);
      }
    }
    // ---- cross-wave reduce of ctx partials, bf16 store ----
#pragma unroll
    for (int j = 0; j < 4; ++j)
#pragma unroll
      for (int qq = 0; qq < 4; ++qq)
        part[wid][g * 4 + qq][j * 16 + r16] = pacc[j][qq];
    __syncthreads();
#pragma unroll
    for (int qi = 0; qi < 4; ++qi) {
      int q = qi * 4 + wid;
      int dk = lane;
      float s = part[0][q][dk] + part[1][q][dk] + part[2][q][dk] + part[3][q][dk];
      ctxb[(size_t)(b * 512 + q0 + q) * 512 + h * 64 + dk] = f2bf(s);
    }
    __syncthreads();  // part/red reused next head
  }
  // ---- KL(avg over heads || uniform) from fp32 head-sums ----
  const float prior = 1.0f / 512.0f + 1e-8f;
  float kl[4] = {0.f, 0.f, 0.f, 0.f};
#pragma unroll
  for (int tt = 0; tt < 8; ++tt)
#pragma unroll
    for (int r = 0; r < 4; ++r) {
      float a = hs[tt][r] * 0.125f + 1e-8f;
      kl[r] += a * __logf(a / prior);
    }
#pragma unroll
  for (int r = 0; r < 4; ++r)
#pragma unroll
    for (int m = 8; m; m >>= 1) kl[r] += __shfl_xor(kl[r], m, 16);
  if (r16 == 0) {
#pragma unroll
    for (int r = 0; r < 4; ++r) klred[wid][g * 4 + r] = kl[r];
  }
  __syncthreads();
  if (tid < 16) {
    float v = klred[0][tid] + klred[1][tid] + klred[2][tid] + klred[3][tid];
    int row = b * 512 + q0 + tid;
    assoc[row] = FIRST ? v : (assoc[row] + v);
  }
}

// ---------------- V transpose: qkvh V-section -> Vt[bh][64 dk][512 t] bf16 ----------------
__global__ __launch_bounds__(256) void vt_kernel(const short* __restrict__ qkvh,
                                                 short* __restrict__ Vt) {
  __shared__ short t[32][34];
  const int bh = blockIdx.z, b = bh >> 3, h = bh & 7;
  const int t0 = blockIdx.x * 32, d0 = blockIdx.y * 32;
  const int tx = threadIdx.x & 31, ty = threadIdx.x >> 5;  // 32 x 8
#pragma unroll
  for (int i = 0; i < 4; i++)
    t[ty + i * 8][tx] = qkvh[(size_t)(b * 512 + t0 + ty + i * 8) * 1536 + 1024 + h * 64 + d0 + tx];
  __syncthreads();
#pragma unroll
  for (int i = 0; i < 4; i++)
    Vt[((size_t)bh * 64 + d0 + ty + i * 8) * 512 + t0 + tx] = t[tx][ty + i * 8];
}

// ---------------- layernorm: h = LN(h + res_bf16)*g + b; fp32 + bf16 out (vectorized) ----------------
__global__ __launch_bounds__(256) void ln_kernel(const float* __restrict__ hin,
                                                 const short* __restrict__ res,
                                                 const float* __restrict__ g,
                                                 const float* __restrict__ bta,
                                                 float* __restrict__ hout, short* __restrict__ hbf) {
  const int wid = threadIdx.x >> 6, lane = threadIdx.x & 63;
  const size_t row = (size_t)blockIdx.x * 4 + wid;
  const float* hp = hin + row * 512 + lane * 8;
  float4v a0 = *(const float4v*)hp;
  float4v a1 = *(const float4v*)(hp + 4);
  bf16x8 rv = *(const bf16x8*)(res + row * 512 + lane * 8);
  float v[8], s = 0.f, s2 = 0.f;
#pragma unroll
  for (int i = 0; i < 8; i++) {
    float base = (i < 4) ? a0[i] : a1[i - 4];
    v[i] = base + bf2f((unsigned short)rv[i]);
    s += v[i];
    s2 += v[i] * v[i];
  }
#pragma unroll
  for (int m = 32; m; m >>= 1) {
    s += __shfl_xor(s, m, 64);
    s2 += __shfl_xor(s2, m, 64);
  }
  float mu = s * (1.0f / 512.0f);
  float var = s2 * (1.0f / 512.0f) - mu * mu;
  float rs = rsqrtf(var + 1e-5f);
  const float* gp = g + lane * 8;
  const float* bp = bta + lane * 8;
  float4v o0, o1;
  bf16x8 ob;
#pragma unroll
  for (int i = 0; i < 8; i++) {
    float y = (v[i] - mu) * rs * gp[i] + bp[i];
    if (i < 4) o0[i] = y; else o1[i - 4] = y;
    ob[i] = f2bf(y);
  }
  float* op = hout + row * 512 + lane * 8;
  *(float4v*)op = o0;
  *(float4v*)(op + 4) = o1;
  *(bf16x8*)(hbf + row * 512 + lane * 8) = ob;
}

// ---------------- reconstruction via MFMA: out[4096,32] = h_bf @ WoutT^T + bout ----------------
__global__ __launch_bounds__(256) void recon_mfma(const short* __restrict__ hbf,
                                                  const short* __restrict__ WoutT,
                                                  const float* __restrict__ bout,
                                                  float* __restrict__ out) {
  const int wid = threadIdx.x >> 6, lane = threadIdx.x & 63;
  const int r16 = lane & 15, kg = (lane >> 4) * 8;
  const int wbase = blockIdx.x * 128 + wid * 32;

  f32x4 acc[2][2];
#pragma unroll
  for (int i = 0; i < 2; i++)
#pragma unroll
    for (int j = 0; j < 2; j++)
#pragma unroll
      for (int q = 0; q < 4; q++) acc[i][j][q] = 0.0f;

  for (int kt = 0; kt < 512; kt += 32) {
    bf16x8 af[2], bfr[2];
#pragma unroll
    for (int i = 0; i < 2; i++)
      af[i] = *(const bf16x8*)&hbf[(size_t)(wbase + i * 16 + r16) * 512 + kt + kg];
#pragma unroll
    for (int j = 0; j < 2; j++)
      bfr[j] = *(const bf16x8*)&WoutT[(size_t)(j * 16 + r16) * 512 + kt + kg];
#pragma unroll
    for (int i = 0; i < 2; i++)
#pragma unroll
      for (int j = 0; j < 2; j++)
        acc[i][j] = __builtin_amdgcn_mfma_f32_16x16x32_bf16(af[i], bfr[j], acc[i][j], 0, 0, 0);
  }

  const int rowg = (lane >> 4) * 4;
#pragma unroll
  for (int i = 0; i < 2; i++)
#pragma unroll
    for (int j = 0; j < 2; j++) {
      int col = j * 16 + r16;
#pragma unroll
      for (int q = 0; q < 4; q++)
        out[(size_t)(wbase + i * 16 + rowg + q) * 32 + col] = acc[i][j][q] + bout[col];
    }
}

// ---------------- score stage 2 + assoc output ----------------
__global__ __launch_bounds__(256) void score2_kernel(const short* __restrict__ s1,
                                                     const float* __restrict__ Ws2,
                                                     const float* __restrict__ bs2,
                                                     const float* __restrict__ assoc,
                                                     float* __restrict__ outScore,
                                                     float* __restrict__ outAssoc) {
  const int wid = threadIdx.x >> 6, lane = threadIdx.x & 63;
  const int row = blockIdx.x * 4 + wid;
  const short* rp = &s1[(size_t)row * 256 + lane * 4];
  float d = 0.f;
#pragma unroll
  for (int e = 0; e < 4; e++) d += bf2f((unsigned short)rp[e]) * Ws2[lane * 4 + e];
#pragma unroll
  for (int m = 32; m; m >>= 1) d += __shfl_xor(d, m, 64);
  if (lane == 0) {
    outScore[row] = 1.f / (1.f + __expf(-(d + bs2[0])));
    outAssoc[row] = assoc[row] * (1.0f / 6.0f);
  }
}

extern "C" void kernel_launch(void* const* d_in, const int* in_sizes, int n_in,
                              void* d_out, int out_size, void* d_ws, size_t ws_size,
                              hipStream_t stream) {
  const float* x    = (const float*)d_in[0];
  const float* W_in = (const float*)d_in[1];
  const float* b_in = (const float*)d_in[2];
  const float* pe   = (const float*)d_in[3];
  const float* Wq   = (const float*)d_in[4];
  const float* Wk   = (const float*)d_in[5];
  const float* Wv   = (const float*)d_in[6];
  const float* Wo   = (const float*)d_in[7];
  const float* bo   = (const float*)d_in[8];
  const float* W1   = (const float*)d_in[9];
  const float* b1   = (const float*)d_in[10];
  const float* W2   = (const float*)d_in[11];
  const float* b2   = (const float*)d_in[12];
  const float* ln1g = (const float*)d_in[13];
  const float* ln1b = (const float*)d_in[14];
  const float* ln2g = (const float*)d_in[15];
  const float* ln2b = (const float*)d_in[16];
  const float* Wout = (const float*)d_in[17];
  const float* bout = (const float*)d_in[18];
  const float* Ws1  = (const float*)d_in[19];
  const float* bs1  = (const float*)d_in[20];
  const float* Ws2  = (const float*)d_in[21];
  const float* bs2  = (const float*)d_in[22];

  char* p = (char*)d_ws;
  auto alloc = [&](size_t bytes) {
    void* r = (void*)p;
    p += (bytes + 255) & ~(size_t)255;
    return r;
  };
  float* h     = (float*)alloc((size_t)4096 * 512 * 4);
  short* h_bf  = (short*)alloc((size_t)4096 * 512 * 2);
  short* qkvh  = (short*)alloc((size_t)4096 * 1536 * 2);
  short* aout  = (short*)alloc((size_t)4096 * 512 * 2);
  short* ctxb  = (short*)alloc((size_t)4096 * 512 * 2);
  short* ff1b  = (short*)alloc((size_t)4096 * 2048 * 2);
  short* ff2   = (short*)alloc((size_t)4096 * 512 * 2);
  float* assoc = (float*)alloc((size_t)4096 * 4);
  short* Vt    = (short*)alloc((size_t)64 * 64 * 512 * 2);
  short* sc1   = (short*)alloc((size_t)4096 * 256 * 2);
  short* qkvt  = (short*)alloc((size_t)6 * 1536 * 512 * 2);
  short* wot   = (short*)alloc((size_t)6 * 512 * 512 * 2);
  short* w1t   = (short*)alloc((size_t)6 * 2048 * 512 * 2);
  short* w2t   = (short*)alloc((size_t)6 * 512 * 2048 * 2);
  short* ws1t  = (short*)alloc((size_t)256 * 512 * 2);
  short* woutT = (short*)alloc((size_t)32 * 512 * 2);

  // weight transpose+convert (per launch; graph-capture safe)
  transpose_qkv<<<dim3(16, 16, 18), 256, 0, stream>>>(Wq, Wk, Wv, qkvt);
  transpose_bf<<<dim3(16, 16, 6), 256, 0, stream>>>(Wo, wot, 512, 512, 262144, 262144);
  transpose_bf<<<dim3(64, 16, 6), 256, 0, stream>>>(W1, w1t, 512, 2048, 1048576, 1048576);
  transpose_bf<<<dim3(16, 64, 6), 256, 0, stream>>>(W2, w2t, 2048, 512, 1048576, 1048576);
  transpose_bf<<<dim3(8, 16, 1), 256, 0, stream>>>(Ws1, ws1t, 512, 256, 0, 0);
  transpose_bf<<<dim3(1, 16, 1), 256, 0, stream>>>(Wout, woutT, 512, 32, 0, 0);

  embed_kernel<<<8192, 256, 0, stream>>>(x, W_in, b_in, pe, h, h_bf);

  for (int l = 0; l < 6; ++l) {
    gemm_bt<3, 128, 128, 32><<<dim3(12, 32), 256, 0, stream>>>(
        h_bf, qkvt + (size_t)l * 786432, nullptr, qkvh, nullptr, 4096, 1536, 512);
    vt_kernel<<<dim3(16, 2, 64), 256, 0, stream>>>(qkvh, Vt);
    if (l == 0)
      attn_fused<1><<<dim3(8, 32), 256, 0, stream>>>(qkvh, Vt, ctxb, assoc);
    else
      attn_fused<0><<<dim3(8, 32), 256, 0, stream>>>(qkvh, Vt, ctxb, assoc);
    gemm_bt<4, 64, 64, 32><<<dim3(8, 64), 256, 0, stream>>>(
        ctxb, wot + (size_t)l * 262144, nullptr, aout, bo + l * 512, 4096, 512, 512);
    ln_kernel<<<1024, 256, 0, stream>>>(h, aout, ln1g + l * 512, ln1b + l * 512, h, h_bf);
    gemm_bt<2, 128, 128, 32><<<dim3(16, 32), 256, 0, stream>>>(
        h_bf, w1t + (size_t)l * 1048576, nullptr, ff1b, b1 + l * 2048, 4096, 2048, 512);
    gemm_bt<4, 64, 64, 32><<<dim3(8, 64), 256, 0, stream>>>(
        ff1b, w2t + (size_t)l * 1048576, nullptr, ff2, b2 + l * 512, 4096, 512, 2048);
    ln_kernel<<<1024, 256, 0, stream>>>(h, ff2, ln2g + l * 512, ln2b + l * 512, h, h_bf);
  }

  float* out = (float*)d_out;
  recon_mfma<<<32, 256, 0, stream>>>(h_bf, woutT, bout, out);
  gemm_bt<2, 128, 128, 32><<<dim3(2, 32), 256, 0, stream>>>(h_bf, ws1t, nullptr, sc1, bs1,
                                                            4096, 256, 512);
  score2_kernel<<<1024, 256, 0, stream>>>(sc1, Ws2, bs2, assoc, out + 131072,
                                          out + 131072 + 4096);
}

// Round 8
// 864.947 us; speedup vs baseline: 1.1298x; 1.1298x over previous
//
#include <hip/hip_runtime.h>
#include <math.h>

typedef __attribute__((ext_vector_type(8))) short bf16x8;
typedef __attribute__((ext_vector_type(4))) float f32x4;
typedef __attribute__((ext_vector_type(4))) float float4v;

__device__ __forceinline__ short f2bf(float v) {
  union { float f; unsigned u; } x; x.f = v;
  unsigned r = x.u + 0x7fffu + ((x.u >> 16) & 1u);
  return (short)(r >> 16);
}

__device__ __forceinline__ float bf2f(unsigned short u) {
  union { unsigned u; float f; } x; x.u = ((unsigned)u) << 16;
  return x.f;
}

__device__ __forceinline__ void gld_lds16(const void* g, void* l) {
  __builtin_amdgcn_global_load_lds((const __attribute__((address_space(1))) void*)g,
                                   (__attribute__((address_space(3))) void*)l, 16, 0, 0);
}

// ---------------- transpose fp32 [R,C] -> bf16 [C,R], batched over z ----------------
__global__ __launch_bounds__(256) void transpose_bf(const float* __restrict__ src,
                                                    short* __restrict__ dst,
                                                    int R, int C, size_t sStride, size_t dStride) {
  __shared__ float t[32][33];
  src += blockIdx.z * sStride;
  dst += blockIdx.z * dStride;
  int tx = threadIdx.x & 31, ty = threadIdx.x >> 5;  // 32 x 8
  int c0 = blockIdx.x * 32, r0 = blockIdx.y * 32;
#pragma unroll
  for (int i = 0; i < 4; i++)
    t[ty + i * 8][tx] = src[(size_t)(r0 + ty + i * 8) * C + c0 + tx];
  __syncthreads();
#pragma unroll
  for (int i = 0; i < 4; i++)
    dst[(size_t)(c0 + ty + i * 8) * R + r0 + tx] = f2bf(t[tx][ty + i * 8]);
}

// ---------------- transpose Wq/Wk/Wv [512,512] fp32 -> qkvt bf16, one dispatch ----------------
__global__ __launch_bounds__(256) void transpose_qkv(const float* __restrict__ Wq,
                                                     const float* __restrict__ Wk,
                                                     const float* __restrict__ Wv,
                                                     short* __restrict__ qkvt) {
  __shared__ float t[32][33];
  const int z = blockIdx.z;           // 0..17
  const int which = z / 6, l = z % 6;
  const float* src = (which == 0 ? Wq : which == 1 ? Wk : Wv) + (size_t)l * 262144;
  short* dst = qkvt + (size_t)l * 786432 + (size_t)which * 262144;
  int tx = threadIdx.x & 31, ty = threadIdx.x >> 5;
  int c0 = blockIdx.x * 32, r0 = blockIdx.y * 32;
#pragma unroll
  for (int i = 0; i < 4; i++)
    t[ty + i * 8][tx] = src[(size_t)(r0 + ty + i * 8) * 512 + c0 + tx];
  __syncthreads();
#pragma unroll
  for (int i = 0; i < 4; i++)
    dst[(size_t)(c0 + ty + i * 8) * 512 + r0 + tx] = f2bf(t[tx][ty + i * 8]);
}

// ---------------- embed: h = x @ W_in + b_in + pe; also bf16 copy ----------------
__global__ void embed_kernel(const float* __restrict__ x, const float* __restrict__ W_in,
                             const float* __restrict__ b_in, const float* __restrict__ pe,
                             float* __restrict__ h, short* __restrict__ hbf) {
  int col = (blockIdx.x & 1) * 256 + threadIdx.x;
  int row = blockIdx.x >> 1;
  int s = row & 511;
  float a = b_in[col] + pe[s * 512 + col];
  const float* xr = x + (size_t)row * 32;
#pragma unroll
  for (int k = 0; k < 32; k++) a += xr[k] * W_in[k * 512 + col];
  h[(size_t)row * 512 + col] = a;
  hbf[(size_t)row * 512 + col] = f2bf(a);
}

// ---------------- bf16 GEMM: A[M,K] x Bt[N,K]^T -> C[M,N] ----------------
// EPI: 0 f32; 1 f32+bias; 2 bf16+bias+relu; 3 bf16; 4 bf16+bias;
//      5 bf16 QKV->dense per-head layout qh[(sect*64+b*8+h)*512+t][dk]
// BK=32: LDS row stride 64B -> only 2-way bank aliasing on ds_read_b128 (free per m136).
// BK=64 measured 4.7M conflicts/dispatch (32-way, 128B stride) -> do not raise BK.
template <int EPI, int BM, int BN, int BK>
__global__ __launch_bounds__(256) void gemm_bt(const short* __restrict__ A,
                                               const short* __restrict__ Bt,
                                               float* __restrict__ Cf, short* __restrict__ Cb,
                                               const float* __restrict__ bias,
                                               int M, int N, int K) {
  __shared__ short As[BM * BK];
  __shared__ short Bs[BN * BK];
  const int tid = threadIdx.x;
  const int wid = tid >> 6;
  const int lane = tid & 63;
  const int m0 = blockIdx.y * BM;
  const int n0 = blockIdx.x * BN;
  constexpr int WR = BM / 2, WC = BN / 2, FI = WR / 16, FJ = WC / 16, KK = BK / 32;
  const int wr = (wid >> 1) * WR;
  const int wc = (wid & 1) * WC;

  f32x4 acc[FI][FJ];
#pragma unroll
  for (int i = 0; i < FI; i++)
#pragma unroll
    for (int j = 0; j < FJ; j++)
#pragma unroll
      for (int q = 0; q < 4; q++) acc[i][j][q] = 0.0f;

  const short* aBase = A + (size_t)m0 * K;
  const short* bBase = Bt + (size_t)n0 * K;
  constexpr int RPC = 512 / BK;        // rows staged per gld_lds call (1024B)
  constexpr int CA = BM / RPC;         // calls for A tile
  constexpr int CT = (BM + BN) / RPC;  // total calls
  const int rowL = lane / (64 / RPC);        // lane's row within a call
  const int colE = (lane % (64 / RPC)) * 8;  // lane's 16B slot (in shorts)
  const int kg = (lane >> 4) * 8;
  const int r16 = lane & 15;

  for (int kt = 0; kt < K; kt += BK) {
    __syncthreads();
#pragma unroll
    for (int c = 0; c < CT / 4; ++c) {
      int s = c * 4 + wid;
      if (s < CA)
        gld_lds16(aBase + (size_t)(s * RPC + rowL) * K + kt + colE, As + s * 512);
      else
        gld_lds16(bBase + (size_t)((s - CA) * RPC + rowL) * K + kt + colE, Bs + (s - CA) * 512);
    }
    __syncthreads();
    bf16x8 af[FI][KK], bfr[FJ][KK];
#pragma unroll
    for (int i = 0; i < FI; i++)
#pragma unroll
      for (int kk = 0; kk < KK; kk++)
        af[i][kk] = *(const bf16x8*)&As[(wr + i * 16 + r16) * BK + kk * 32 + kg];
#pragma unroll
    for (int j = 0; j < FJ; j++)
#pragma unroll
      for (int kk = 0; kk < KK; kk++)
        bfr[j][kk] = *(const bf16x8*)&Bs[(wc + j * 16 + r16) * BK + kk * 32 + kg];
#pragma unroll
    for (int kk = 0; kk < KK; kk++)
#pragma unroll
      for (int i = 0; i < FI; i++)
#pragma unroll
        for (int j = 0; j < FJ; j++)
          acc[i][j] = __builtin_amdgcn_mfma_f32_16x16x32_bf16(af[i][kk], bfr[j][kk], acc[i][j], 0, 0, 0);
  }

  const int col16 = lane & 15;
  const int rowg = (lane >> 4) * 4;
#pragma unroll
  for (int i = 0; i < FI; i++) {
    int row = m0 + wr + i * 16 + rowg;
#pragma unroll
    for (int j = 0; j < FJ; j++) {
      int col = n0 + wc + j * 16 + col16;
      float bv = (EPI == 1 || EPI == 2 || EPI == 4) ? bias[col] : 0.0f;
#pragma unroll
      for (int q = 0; q < 4; q++) {
        float v = acc[i][j][q] + bv;
        if (EPI == 2) {
          v = fmaxf(v, 0.0f);
          Cb[(size_t)(row + q) * N + col] = f2bf(v);
        } else if (EPI == 5) {
          int rr = row + q;
          int sect = col >> 9, hh = (col >> 6) & 7, dk = col & 63;
          int bq = rr >> 9, tt = rr & 511;
          Cb[(((size_t)(sect * 64 + bq * 8 + hh)) * 512 + tt) * 64 + dk] = f2bf(v);
        } else if (EPI == 3 || EPI == 4) {
          Cb[(size_t)(row + q) * N + col] = f2bf(v);
        } else {
          Cf[(size_t)(row + q) * N + col] = v;
        }
      }
    }
  }
}

// ---------------- V-transpose (4 tiles) + scores + softmax + P write ----------------
// qh: dense per-head [sect*64+bh][t][64]. Phase A: this block transposes its 4 of the
// 2048 V 32x32 tiles into Vt (pv consumes next kernel). Phase B: QK^T + softmax + P.
__global__ __launch_bounds__(256) void smvt_kernel(const short* __restrict__ qh,
                                                   short* __restrict__ P,
                                                   short* __restrict__ Vt) {
  __shared__ short tb[32][34];
  const int bh = blockIdx.y;
  const int q0 = blockIdx.x * 64;
  const int tid = threadIdx.x;
  const int wid = tid >> 6, lane = tid & 63;
  const int r16 = lane & 15, g = lane >> 4;

  // ---- phase A: V transpose, 4 of 32 tiles for this bh ----
  {
    const short* Vh = qh + ((size_t)(128 + bh) * 512) * 64;
    const int tx = tid & 31, ty = tid >> 5;
#pragma unroll
    for (int i = 0; i < 4; ++i) {
      const int idx = blockIdx.x * 4 + i;
      const int t0 = (idx & 15) * 32, d0 = (idx >> 4) * 32;
      __syncthreads();
#pragma unroll
      for (int r = 0; r < 4; ++r)
        tb[ty + r * 8][tx] = Vh[(size_t)(t0 + ty + r * 8) * 64 + d0 + tx];
      __syncthreads();
#pragma unroll
      for (int r = 0; r < 4; ++r)
        Vt[((size_t)bh * 64 + d0 + ty + r * 8) * 512 + t0 + tx] = tb[tx][ty + r * 8];
    }
  }

  // ---- phase B: QK^T (dense 128B rows) ----
  const short* Qh = qh + ((size_t)bh * 512) * 64;
  const short* Kh = qh + ((size_t)(64 + bh) * 512) * 64;
  const short* qp = Qh + (size_t)(q0 + wid * 16 + r16) * 64 + g * 8;
  const bf16x8 qa0 = *(const bf16x8*)qp;
  const bf16x8 qa1 = *(const bf16x8*)(qp + 32);

  f32x4 acc[32];
#pragma unroll
  for (int tt = 0; tt < 32; ++tt) {
    const short* kp = Kh + (size_t)(tt * 16 + r16) * 64 + g * 8;
    bf16x8 kb0 = *(const bf16x8*)kp;
    bf16x8 kb1 = *(const bf16x8*)(kp + 32);
    f32x4 c = {0.f, 0.f, 0.f, 0.f};
    c = __builtin_amdgcn_mfma_f32_16x16x32_bf16(qa0, kb0, c, 0, 0, 0);
    c = __builtin_amdgcn_mfma_f32_16x16x32_bf16(qa1, kb1, c, 0, 0, 0);
    acc[tt] = c;
  }

  float mx[4] = {-1e30f, -1e30f, -1e30f, -1e30f};
#pragma unroll
  for (int tt = 0; tt < 32; ++tt)
#pragma unroll
    for (int r = 0; r < 4; ++r) mx[r] = fmaxf(mx[r], acc[tt][r]);
#pragma unroll
  for (int r = 0; r < 4; ++r)
#pragma unroll
    for (int m = 8; m; m >>= 1) mx[r] = fmaxf(mx[r], __shfl_xor(mx[r], m, 16));

  float sum[4] = {0.f, 0.f, 0.f, 0.f};
#pragma unroll
  for (int tt = 0; tt < 32; ++tt)
#pragma unroll
    for (int r = 0; r < 4; ++r) {
      float e = __expf((acc[tt][r] - mx[r]) * 0.125f);
      sum[r] += e;
      acc[tt][r] = e;
    }
#pragma unroll
  for (int r = 0; r < 4; ++r)
#pragma unroll
    for (int m = 8; m; m >>= 1) sum[r] += __shfl_xor(sum[r], m, 16);
  float inv[4];
#pragma unroll
  for (int r = 0; r < 4; ++r) inv[r] = 1.0f / sum[r];

  short* prow = P + ((size_t)bh * 512 + q0 + wid * 16 + g * 4) * 512 + r16;
#pragma unroll
  for (int r = 0; r < 4; ++r)
#pragma unroll
    for (int tt = 0; tt < 32; ++tt)
      prow[(size_t)r * 512 + tt * 16] = f2bf(acc[tt][r] * inv[r]);
}

// ---------------- ctx = P @ V : per (b,h), tile 128x64 ----------------
__global__ __launch_bounds__(256) void pv_gemm(const short* __restrict__ P,
                                               const short* __restrict__ Vt,
                                               short* __restrict__ ctxb) {
  __shared__ short As[128 * 32];
  __shared__ short Bs[64 * 32];
  const int bh = blockIdx.y, b = bh >> 3, h = bh & 7;
  const int m0 = blockIdx.x * 128;
  const int tid = threadIdx.x, wid = tid >> 6, lane = tid & 63;
  const short* aBase = P + ((size_t)bh * 512 + m0) * 512;
  const short* bBase = Vt + (size_t)bh * 64 * 512;
  const int rowA0 = lane >> 2, colE = (lane & 3) * 8, kg = (lane >> 4) * 8, r16 = lane & 15;

  f32x4 acc[2][4];
#pragma unroll
  for (int i = 0; i < 2; i++)
#pragma unroll
    for (int j = 0; j < 4; j++)
#pragma unroll
      for (int q = 0; q < 4; q++) acc[i][j][q] = 0.0f;

  for (int kt = 0; kt < 512; kt += 32) {
    __syncthreads();
    gld_lds16(aBase + (size_t)(wid * 16 + rowA0) * 512 + kt + colE, As + wid * 512);
    gld_lds16(aBase + (size_t)((wid + 4) * 16 + rowA0) * 512 + kt + colE, As + (wid + 4) * 512);
    gld_lds16(bBase + (size_t)(wid * 16 + rowA0) * 512 + kt + colE, Bs + wid * 512);
    __syncthreads();
    bf16x8 af[2], bfr[4];
#pragma unroll
    for (int i = 0; i < 2; i++)
      af[i] = *(const bf16x8*)&As[(wid * 32 + i * 16 + r16) * 32 + kg];
#pragma unroll
    for (int j = 0; j < 4; j++)
      bfr[j] = *(const bf16x8*)&Bs[(j * 16 + r16) * 32 + kg];
#pragma unroll
    for (int i = 0; i < 2; i++)
#pragma unroll
      for (int j = 0; j < 4; j++)
        acc[i][j] = __builtin_amdgcn_mfma_f32_16x16x32_bf16(af[i], bfr[j], acc[i][j], 0, 0, 0);
  }

  const int rowg = (lane >> 4) * 4;
#pragma unroll
  for (int i = 0; i < 2; i++) {
    int row = m0 + wid * 32 + i * 16 + rowg;
#pragma unroll
    for (int j = 0; j < 4; j++) {
      int col = h * 64 + j * 16 + r16;
#pragma unroll
      for (int q = 0; q < 4; q++)
        ctxb[(size_t)(b * 512 + row + q) * 512 + col] = f2bf(acc[i][j][q]);
    }
  }
}

// ---------------- KL(avg_attn || uniform) per query row; one wave per row ----------------
template <int FIRST>
__global__ __launch_bounds__(256) void kl_kernel(const short* __restrict__ P,
                                                 float* __restrict__ assoc) {
  const int wid = threadIdx.x >> 6, lane = threadIdx.x & 63;
  const int row = blockIdx.x * 4 + wid;  // b*512 + q
  const int b = row >> 9, q = row & 511;
  const float prior = 1.0f / 512.0f + 1e-8f;
  float hs[8] = {0.f, 0.f, 0.f, 0.f, 0.f, 0.f, 0.f, 0.f};
#pragma unroll
  for (int h = 0; h < 8; ++h) {
    bf16x8 v = *(const bf16x8*)&P[(((size_t)(b * 8 + h)) * 512 + q) * 512 + lane * 8];
#pragma unroll
    for (int k = 0; k < 8; ++k) hs[k] += bf2f((unsigned short)v[k]);
  }
  float s = 0.f;
#pragma unroll
  for (int k = 0; k < 8; ++k) {
    float a = hs[k] * 0.125f + 1e-8f;
    s += a * __logf(a / prior);
  }
#pragma unroll
  for (int m = 32; m; m >>= 1) s += __shfl_xor(s, m, 64);
  if (lane == 0) assoc[row] = FIRST ? s : (assoc[row] + s);
}

// ---------------- layernorm: h = LN(h + res_bf16)*g + b; fp32 + bf16 out (vectorized) ----------------
__global__ __launch_bounds__(256) void ln_kernel(const float* __restrict__ hin,
                                                 const short* __restrict__ res,
                                                 const float* __restrict__ g,
                                                 const float* __restrict__ bta,
                                                 float* __restrict__ hout, short* __restrict__ hbf) {
  const int wid = threadIdx.x >> 6, lane = threadIdx.x & 63;
  const size_t row = (size_t)blockIdx.x * 4 + wid;
  const float* hp = hin + row * 512 + lane * 8;
  float4v a0 = *(const float4v*)hp;
  float4v a1 = *(const float4v*)(hp + 4);
  bf16x8 rv = *(const bf16x8*)(res + row * 512 + lane * 8);
  float v[8], s = 0.f, s2 = 0.f;
#pragma unroll
  for (int i = 0; i < 8; i++) {
    float base = (i < 4) ? a0[i] : a1[i - 4];
    v[i] = base + bf2f((unsigned short)rv[i]);
    s += v[i];
    s2 += v[i] * v[i];
  }
#pragma unroll
  for (int m = 32; m; m >>= 1) {
    s += __shfl_xor(s, m, 64);
    s2 += __shfl_xor(s2, m, 64);
  }
  float mu = s * (1.0f / 512.0f);
  float var = s2 * (1.0f / 512.0f) - mu * mu;
  float rs = rsqrtf(var + 1e-5f);
  const float* gp = g + lane * 8;
  const float* bp = bta + lane * 8;
  float4v o0, o1;
  bf16x8 ob;
#pragma unroll
  for (int i = 0; i < 8; i++) {
    float y = (v[i] - mu) * rs * gp[i] + bp[i];
    if (i < 4) o0[i] = y; else o1[i - 4] = y;
    ob[i] = f2bf(y);
  }
  float* op = hout + row * 512 + lane * 8;
  *(float4v*)op = o0;
  *(float4v*)(op + 4) = o1;
  *(bf16x8*)(hbf + row * 512 + lane * 8) = ob;
}

// ---------------- reconstruction via MFMA: out[4096,32] = h_bf @ WoutT^T + bout ----------------
__global__ __launch_bounds__(256) void recon_mfma(const short* __restrict__ hbf,
                                                  const short* __restrict__ WoutT,
                                                  const float* __restrict__ bout,
                                                  float* __restrict__ out) {
  const int wid = threadIdx.x >> 6, lane = threadIdx.x & 63;
  const int r16 = lane & 15, kg = (lane >> 4) * 8;
  const int wbase = blockIdx.x * 128 + wid * 32;

  f32x4 acc[2][2];
#pragma unroll
  for (int i = 0; i < 2; i++)
#pragma unroll
    for (int j = 0; j < 2; j++)
#pragma unroll
      for (int q = 0; q < 4; q++) acc[i][j][q] = 0.0f;

  for (int kt = 0; kt < 512; kt += 32) {
    bf16x8 af[2], bfr[2];
#pragma unroll
    for (int i = 0; i < 2; i++)
      af[i] = *(const bf16x8*)&hbf[(size_t)(wbase + i * 16 + r16) * 512 + kt + kg];
#pragma unroll
    for (int j = 0; j < 2; j++)
      bfr[j] = *(const bf16x8*)&WoutT[(size_t)(j * 16 + r16) * 512 + kt + kg];
#pragma unroll
    for (int i = 0; i < 2; i++)
#pragma unroll
      for (int j = 0; j < 2; j++)
        acc[i][j] = __builtin_amdgcn_mfma_f32_16x16x32_bf16(af[i], bfr[j], acc[i][j], 0, 0, 0);
  }

  const int rowg = (lane >> 4) * 4;
#pragma unroll
  for (int i = 0; i < 2; i++)
#pragma unroll
    for (int j = 0; j < 2; j++) {
      int col = j * 16 + r16;
#pragma unroll
      for (int q = 0; q < 4; q++)
        out[(size_t)(wbase + i * 16 + rowg + q) * 32 + col] = acc[i][j][q] + bout[col];
    }
}

// ---------------- score stage 2 + assoc output ----------------
__global__ __launch_bounds__(256) void score2_kernel(const short* __restrict__ s1,
                                                     const float* __restrict__ Ws2,
                                                     const float* __restrict__ bs2,
                                                     const float* __restrict__ assoc,
                                                     float* __restrict__ outScore,
                                                     float* __restrict__ outAssoc) {
  const int wid = threadIdx.x >> 6, lane = threadIdx.x & 63;
  const int row = blockIdx.x * 4 + wid;
  const short* rp = &s1[(size_t)row * 256 + lane * 4];
  float d = 0.f;
#pragma unroll
  for (int e = 0; e < 4; e++) d += bf2f((unsigned short)rp[e]) * Ws2[lane * 4 + e];
#pragma unroll
  for (int m = 32; m; m >>= 1) d += __shfl_xor(d, m, 64);
  if (lane == 0) {
    outScore[row] = 1.f / (1.f + __expf(-(d + bs2[0])));
    outAssoc[row] = assoc[row] * (1.0f / 6.0f);
  }
}

extern "C" void kernel_launch(void* const* d_in, const int* in_sizes, int n_in,
                              void* d_out, int out_size, void* d_ws, size_t ws_size,
                              hipStream_t stream) {
  const float* x    = (const float*)d_in[0];
  const float* W_in = (const float*)d_in[1];
  const float* b_in = (const float*)d_in[2];
  const float* pe   = (const float*)d_in[3];
  const float* Wq   = (const float*)d_in[4];
  const float* Wk   = (const float*)d_in[5];
  const float* Wv   = (const float*)d_in[6];
  const float* Wo   = (const float*)d_in[7];
  const float* bo   = (const float*)d_in[8];
  const float* W1   = (const float*)d_in[9];
  const float* b1   = (const float*)d_in[10];
  const float* W2   = (const float*)d_in[11];
  const float* b2   = (const float*)d_in[12];
  const float* ln1g = (const float*)d_in[13];
  const float* ln1b = (const float*)d_in[14];
  const float* ln2g = (const float*)d_in[15];
  const float* ln2b = (const float*)d_in[16];
  const float* Wout = (const float*)d_in[17];
  const float* bout = (const float*)d_in[18];
  const float* Ws1  = (const float*)d_in[19];
  const float* bs1  = (const float*)d_in[20];
  const float* Ws2  = (const float*)d_in[21];
  const float* bs2  = (const float*)d_in[22];

  char* p = (char*)d_ws;
  auto alloc = [&](size_t bytes) {
    void* r = (void*)p;
    p += (bytes + 255) & ~(size_t)255;
    return r;
  };
  float* h     = (float*)alloc((size_t)4096 * 512 * 4);
  short* h_bf  = (short*)alloc((size_t)4096 * 512 * 2);
  short* qh    = (short*)alloc((size_t)4096 * 1536 * 2);  // dense [sect*64+bh][t][64]
  short* aout  = (short*)alloc((size_t)4096 * 512 * 2);
  short* ctxb  = (short*)alloc((size_t)4096 * 512 * 2);
  short* ff1b  = (short*)alloc((size_t)4096 * 2048 * 2);
  short* ff2   = (short*)alloc((size_t)4096 * 512 * 2);
  float* assoc = (float*)alloc((size_t)4096 * 4);
  short* Pbuf  = (short*)alloc((size_t)64 * 512 * 512 * 2);
  short* Vt    = (short*)alloc((size_t)64 * 64 * 512 * 2);
  short* sc1   = (short*)alloc((size_t)4096 * 256 * 2);
  short* qkvt  = (short*)alloc((size_t)6 * 1536 * 512 * 2);
  short* wot   = (short*)alloc((size_t)6 * 512 * 512 * 2);
  short* w1t   = (short*)alloc((size_t)6 * 2048 * 512 * 2);
  short* w2t   = (short*)alloc((size_t)6 * 512 * 2048 * 2);
  short* ws1t  = (short*)alloc((size_t)256 * 512 * 2);
  short* woutT = (short*)alloc((size_t)32 * 512 * 2);

  // weight transpose+convert (per launch; graph-capture safe)
  transpose_qkv<<<dim3(16, 16, 18), 256, 0, stream>>>(Wq, Wk, Wv, qkvt);
  transpose_bf<<<dim3(16, 16, 6), 256, 0, stream>>>(Wo, wot, 512, 512, 262144, 262144);
  transpose_bf<<<dim3(64, 16, 6), 256, 0, stream>>>(W1, w1t, 512, 2048, 1048576, 1048576);
  transpose_bf<<<dim3(16, 64, 6), 256, 0, stream>>>(W2, w2t, 2048, 512, 1048576, 1048576);
  transpose_bf<<<dim3(8, 16, 1), 256, 0, stream>>>(Ws1, ws1t, 512, 256, 0, 0);
  transpose_bf<<<dim3(1, 16, 1), 256, 0, stream>>>(Wout, woutT, 512, 32, 0, 0);

  embed_kernel<<<8192, 256, 0, stream>>>(x, W_in, b_in, pe, h, h_bf);

  for (int l = 0; l < 6; ++l) {
    gemm_bt<5, 128, 128, 32><<<dim3(12, 32), 256, 0, stream>>>(
        h_bf, qkvt + (size_t)l * 786432, nullptr, qh, nullptr, 4096, 1536, 512);
    smvt_kernel<<<dim3(8, 64), 256, 0, stream>>>(qh, Pbuf, Vt);
    pv_gemm<<<dim3(4, 64), 256, 0, stream>>>(Pbuf, Vt, ctxb);
    if (l == 0)
      kl_kernel<1><<<1024, 256, 0, stream>>>(Pbuf, assoc);
    else
      kl_kernel<0><<<1024, 256, 0, stream>>>(Pbuf, assoc);
    gemm_bt<4, 64, 64, 32><<<dim3(8, 64), 256, 0, stream>>>(
        ctxb, wot + (size_t)l * 262144, nullptr, aout, bo + l * 512, 4096, 512, 512);
    ln_kernel<<<1024, 256, 0, stream>>>(h, aout, ln1g + l * 512, ln1b + l * 512, h, h_bf);
    gemm_bt<2, 128, 128, 32><<<dim3(16, 32), 256, 0, stream>>>(
        h_bf, w1t + (size_t)l * 1048576, nullptr, ff1b, b1 + l * 2048, 4096, 2048, 512);
    gemm_bt<4, 64, 64, 32><<<dim3(8, 64), 256, 0, stream>>>(
        ff1b, w2t + (size_t)l * 1048576, nullptr, ff2, b2 + l * 512, 4096, 512, 2048);
    ln_kernel<<<1024, 256, 0, stream>>>(h, ff2, ln2g + l * 512, ln2b + l * 512, h, h_bf);
  }

  float* out = (float*)d_out;
  recon_mfma<<<32, 256, 0, stream>>>(h_bf, woutT, bout, out);
  gemm_bt<2, 128, 128, 32><<<dim3(2, 32), 256, 0, stream>>>(h_bf, ws1t, nullptr, sc1, bs1,
                                                            4096, 256, 512);
  score2_kernel<<<1024, 256, 0, stream>>>(sc1, Ws2, bs2, assoc, out + 131072,
                                          out + 131072 + 4096);
}

// Round 9
// 864.748 us; speedup vs baseline: 1.1301x; 1.0002x over previous
//
#include <hip/hip_runtime.h>
#include <math.h>

typedef __attribute__((ext_vector_type(8))) short bf16x8;
typedef __attribute__((ext_vector_type(4))) float f32x4;
typedef __attribute__((ext_vector_type(4))) float float4v;

__device__ __forceinline__ short f2bf(float v) {
  union { float f; unsigned u; } x; x.f = v;
  unsigned r = x.u + 0x7fffu + ((x.u >> 16) & 1u);
  return (short)(r >> 16);
}

__device__ __forceinline__ float bf2f(unsigned short u) {
  union { unsigned u; float f; } x; x.u = ((unsigned)u) << 16;
  return x.f;
}

__device__ __forceinline__ void gld_lds16(const void* g, void* l) {
  __builtin_amdgcn_global_load_lds((const __attribute__((address_space(1))) void*)g,
                                   (__attribute__((address_space(3))) void*)l, 16, 0, 0);
}

// ---------------- transpose fp32 [R,C] -> bf16 [C,R], batched over z ----------------
__global__ __launch_bounds__(256) void transpose_bf(const float* __restrict__ src,
                                                    short* __restrict__ dst,
                                                    int R, int C, size_t sStride, size_t dStride) {
  __shared__ float t[32][33];
  src += blockIdx.z * sStride;
  dst += blockIdx.z * dStride;
  int tx = threadIdx.x & 31, ty = threadIdx.x >> 5;  // 32 x 8
  int c0 = blockIdx.x * 32, r0 = blockIdx.y * 32;
#pragma unroll
  for (int i = 0; i < 4; i++)
    t[ty + i * 8][tx] = src[(size_t)(r0 + ty + i * 8) * C + c0 + tx];
  __syncthreads();
#pragma unroll
  for (int i = 0; i < 4; i++)
    dst[(size_t)(c0 + ty + i * 8) * R + r0 + tx] = f2bf(t[tx][ty + i * 8]);
}

// ---------------- transpose Wq/Wk/Wv [512,512] fp32 -> qkvt bf16, one dispatch ----------------
__global__ __launch_bounds__(256) void transpose_qkv(const float* __restrict__ Wq,
                                                     const float* __restrict__ Wk,
                                                     const float* __restrict__ Wv,
                                                     short* __restrict__ qkvt) {
  __shared__ float t[32][33];
  const int z = blockIdx.z;           // 0..17
  const int which = z / 6, l = z % 6;
  const float* src = (which == 0 ? Wq : which == 1 ? Wk : Wv) + (size_t)l * 262144;
  short* dst = qkvt + (size_t)l * 786432 + (size_t)which * 262144;
  int tx = threadIdx.x & 31, ty = threadIdx.x >> 5;
  int c0 = blockIdx.x * 32, r0 = blockIdx.y * 32;
#pragma unroll
  for (int i = 0; i < 4; i++)
    t[ty + i * 8][tx] = src[(size_t)(r0 + ty + i * 8) * 512 + c0 + tx];
  __syncthreads();
#pragma unroll
  for (int i = 0; i < 4; i++)
    dst[(size_t)(c0 + ty + i * 8) * 512 + r0 + tx] = f2bf(t[tx][ty + i * 8]);
}

// ---------------- embed: h = x @ W_in + b_in + pe; also bf16 copy ----------------
__global__ void embed_kernel(const float* __restrict__ x, const float* __restrict__ W_in,
                             const float* __restrict__ b_in, const float* __restrict__ pe,
                             float* __restrict__ h, short* __restrict__ hbf) {
  int col = (blockIdx.x & 1) * 256 + threadIdx.x;
  int row = blockIdx.x >> 1;
  int s = row & 511;
  float a = b_in[col] + pe[s * 512 + col];
  const float* xr = x + (size_t)row * 32;
#pragma unroll
  for (int k = 0; k < 32; k++) a += xr[k] * W_in[k * 512 + col];
  h[(size_t)row * 512 + col] = a;
  hbf[(size_t)row * 512 + col] = f2bf(a);
}

// ---------------- bf16 GEMM: A[M,K] x Bt[N,K]^T -> C[M,N] ----------------
// EPI: 0 f32; 1 f32+bias; 2 bf16+bias+relu; 3 bf16; 4 bf16+bias;
//      5 bf16 QKV->dense per-head layout qh[(sect*64+b*8+h)*512+t][dk]
// BK=32: LDS row stride 64B -> only 2-way bank aliasing on ds_read_b128 (free per m136).
// BK=64 measured 4.7M conflicts/dispatch (32-way, 128B stride) -> do not raise BK.
template <int EPI, int BM, int BN, int BK>
__global__ __launch_bounds__(256) void gemm_bt(const short* __restrict__ A,
                                               const short* __restrict__ Bt,
                                               float* __restrict__ Cf, short* __restrict__ Cb,
                                               const float* __restrict__ bias,
                                               int M, int N, int K) {
  __shared__ short As[BM * BK];
  __shared__ short Bs[BN * BK];
  const int tid = threadIdx.x;
  const int wid = tid >> 6;
  const int lane = tid & 63;
  const int m0 = blockIdx.y * BM;
  const int n0 = blockIdx.x * BN;
  constexpr int WR = BM / 2, WC = BN / 2, FI = WR / 16, FJ = WC / 16, KK = BK / 32;
  const int wr = (wid >> 1) * WR;
  const int wc = (wid & 1) * WC;

  f32x4 acc[FI][FJ];
#pragma unroll
  for (int i = 0; i < FI; i++)
#pragma unroll
    for (int j = 0; j < FJ; j++)
#pragma unroll
      for (int q = 0; q < 4; q++) acc[i][j][q] = 0.0f;

  const short* aBase = A + (size_t)m0 * K;
  const short* bBase = Bt + (size_t)n0 * K;
  constexpr int RPC = 512 / BK;        // rows staged per gld_lds call (1024B)
  constexpr int CA = BM / RPC;         // calls for A tile
  constexpr int CT = (BM + BN) / RPC;  // total calls
  const int rowL = lane / (64 / RPC);        // lane's row within a call
  const int colE = (lane % (64 / RPC)) * 8;  // lane's 16B slot (in shorts)
  const int kg = (lane >> 4) * 8;
  const int r16 = lane & 15;

  for (int kt = 0; kt < K; kt += BK) {
    __syncthreads();
#pragma unroll
    for (int c = 0; c < CT / 4; ++c) {
      int s = c * 4 + wid;
      if (s < CA)
        gld_lds16(aBase + (size_t)(s * RPC + rowL) * K + kt + colE, As + s * 512);
      else
        gld_lds16(bBase + (size_t)((s - CA) * RPC + rowL) * K + kt + colE, Bs + (s - CA) * 512);
    }
    __syncthreads();
    bf16x8 af[FI][KK], bfr[FJ][KK];
#pragma unroll
    for (int i = 0; i < FI; i++)
#pragma unroll
      for (int kk = 0; kk < KK; kk++)
        af[i][kk] = *(const bf16x8*)&As[(wr + i * 16 + r16) * BK + kk * 32 + kg];
#pragma unroll
    for (int j = 0; j < FJ; j++)
#pragma unroll
      for (int kk = 0; kk < KK; kk++)
        bfr[j][kk] = *(const bf16x8*)&Bs[(wc + j * 16 + r16) * BK + kk * 32 + kg];
#pragma unroll
    for (int kk = 0; kk < KK; kk++)
#pragma unroll
      for (int i = 0; i < FI; i++)
#pragma unroll
        for (int j = 0; j < FJ; j++)
          acc[i][j] = __builtin_amdgcn_mfma_f32_16x16x32_bf16(af[i][kk], bfr[j][kk], acc[i][j], 0, 0, 0);
  }

  const int col16 = lane & 15;
  const int rowg = (lane >> 4) * 4;
#pragma unroll
  for (int i = 0; i < FI; i++) {
    int row = m0 + wr + i * 16 + rowg;
#pragma unroll
    for (int j = 0; j < FJ; j++) {
      int col = n0 + wc + j * 16 + col16;
      float bv = (EPI == 1 || EPI == 2 || EPI == 4) ? bias[col] : 0.0f;
#pragma unroll
      for (int q = 0; q < 4; q++) {
        float v = acc[i][j][q] + bv;
        if (EPI == 2) {
          v = fmaxf(v, 0.0f);
          Cb[(size_t)(row + q) * N + col] = f2bf(v);
        } else if (EPI == 5) {
          int rr = row + q;
          int sect = col >> 9, hh = (col >> 6) & 7, dk = col & 63;
          int bq = rr >> 9, tt = rr & 511;
          Cb[(((size_t)(sect * 64 + bq * 8 + hh)) * 512 + tt) * 64 + dk] = f2bf(v);
        } else if (EPI == 3 || EPI == 4) {
          Cb[(size_t)(row + q) * N + col] = f2bf(v);
        } else {
          Cf[(size_t)(row + q) * N + col] = v;
        }
      }
    }
  }
}

// ---------------- V transpose (dense layout): qh V-section -> Vt[bh][64 dk][512 t] ----------------
__global__ __launch_bounds__(256) void vt_kernel(const short* __restrict__ qh,
                                                 short* __restrict__ Vt) {
  __shared__ short t[32][34];
  const int bh = blockIdx.z;
  const int t0 = blockIdx.x * 32, d0 = blockIdx.y * 32;
  const int tx = threadIdx.x & 31, ty = threadIdx.x >> 5;  // 32 x 8
  const short* Vh = qh + (size_t)(128 + bh) * 512 * 64;
#pragma unroll
  for (int i = 0; i < 4; i++)
    t[ty + i * 8][tx] = Vh[(size_t)(t0 + ty + i * 8) * 64 + d0 + tx];
  __syncthreads();
#pragma unroll
  for (int i = 0; i < 4; i++)
    Vt[((size_t)bh * 64 + d0 + ty + i * 8) * 512 + t0 + tx] = t[tx][ty + i * 8];
}

// ---------------- fused scores+softmax+P(coalesced dump)+PV: per (bh, 32-query tile) ----------------
// 1024 blocks (~4/CU), 3 block-barriers total (no head loop — r7's failure was 24 barriers
// at 1 block/CU). QK^T splits t across waves; PV splits dk (no cross-wave ctx reduce).
// P staged in 32KB swizzled LDS (byte ^ (q&7)<<4): PV ds reads 2-way alias = free.
__global__ __launch_bounds__(256) void smpv_kernel(const short* __restrict__ qh,
                                                   const short* __restrict__ Vt,
                                                   short* __restrict__ P,
                                                   short* __restrict__ ctxb) {
  __shared__ short Pl[32 * 512];    // 32KB, [q][t] bf16, swizzled
  __shared__ float red0[2][2][16];  // [t_half][q_half][q] max
  __shared__ float red1[2][2][16];  // [t_half][q_half][q] sum
  const int bh = blockIdx.y, b = bh >> 3, h = bh & 7;
  const int q0 = blockIdx.x * 32;
  const int tid = threadIdx.x;
  const int wid = tid >> 6, lane = tid & 63;
  const int r16 = lane & 15, g = lane >> 4;
  const int qh_ = wid & 1, th_ = wid >> 1;

  const short* Qh = qh + ((size_t)bh * 512) * 64;
  const short* Kh = qh + ((size_t)(64 + bh) * 512) * 64;

  // ---- QK^T: rows q0+qh_*16+g*4+r, cols t = th_*256 + tt*16 + r16 ----
  const short* qp = Qh + (size_t)(q0 + qh_ * 16 + r16) * 64 + g * 8;
  const bf16x8 qa0 = *(const bf16x8*)qp;
  const bf16x8 qa1 = *(const bf16x8*)(qp + 32);

  f32x4 acc[16];
#pragma unroll
  for (int tt = 0; tt < 16; ++tt) {
    const short* kp = Kh + (size_t)(th_ * 256 + tt * 16 + r16) * 64 + g * 8;
    bf16x8 kb0 = *(const bf16x8*)kp;
    bf16x8 kb1 = *(const bf16x8*)(kp + 32);
    f32x4 c = {0.f, 0.f, 0.f, 0.f};
    c = __builtin_amdgcn_mfma_f32_16x16x32_bf16(qa0, kb0, c, 0, 0, 0);
    c = __builtin_amdgcn_mfma_f32_16x16x32_bf16(qa1, kb1, c, 0, 0, 0);
    acc[tt] = c;
  }

  // ---- softmax: 16-lane reduce within t-half, then 2-way cross-wave via LDS ----
  float mx[4] = {-1e30f, -1e30f, -1e30f, -1e30f};
#pragma unroll
  for (int tt = 0; tt < 16; ++tt)
#pragma unroll
    for (int r = 0; r < 4; ++r) mx[r] = fmaxf(mx[r], acc[tt][r]);
#pragma unroll
  for (int r = 0; r < 4; ++r)
#pragma unroll
    for (int m = 8; m; m >>= 1) mx[r] = fmaxf(mx[r], __shfl_xor(mx[r], m, 16));
  if (r16 == 0) {
#pragma unroll
    for (int r = 0; r < 4; ++r) red0[th_][qh_][g * 4 + r] = mx[r];
  }
  __syncthreads();
#pragma unroll
  for (int r = 0; r < 4; ++r) {
    int q = g * 4 + r;
    mx[r] = fmaxf(red0[0][qh_][q], red0[1][qh_][q]);
  }
  float sum[4] = {0.f, 0.f, 0.f, 0.f};
#pragma unroll
  for (int tt = 0; tt < 16; ++tt)
#pragma unroll
    for (int r = 0; r < 4; ++r) {
      float e = __expf((acc[tt][r] - mx[r]) * 0.125f);
      acc[tt][r] = e;
      sum[r] += e;
    }
#pragma unroll
  for (int r = 0; r < 4; ++r)
#pragma unroll
    for (int m = 8; m; m >>= 1) sum[r] += __shfl_xor(sum[r], m, 16);
  if (r16 == 0) {
#pragma unroll
    for (int r = 0; r < 4; ++r) red1[th_][qh_][g * 4 + r] = sum[r];
  }
  __syncthreads();

  // ---- P -> swizzled LDS ----
  char* plc = (char*)Pl;
#pragma unroll
  for (int r = 0; r < 4; ++r) {
    int q = qh_ * 16 + g * 4 + r;
    float inv = 1.0f / (red1[0][qh_][g * 4 + r] + red1[1][qh_][g * 4 + r]);
    int swz = (q & 7) << 4;
#pragma unroll
    for (int tt = 0; tt < 16; ++tt)
      *(short*)(plc + q * 1024 + (((th_ * 256 + tt * 16 + r16) * 2) ^ swz)) =
          f2bf(acc[tt][r] * inv);
  }
  __syncthreads();

  // ---- coalesced P dump to global (for kl); stores overlap following MFMA ----
  short* pg = P + ((size_t)bh * 512 + q0) * 512;
#pragma unroll
  for (int rr = 0; rr < 8; ++rr) {
    int q = wid * 8 + rr;
    bf16x8 v = *(const bf16x8*)(plc + q * 1024 + ((lane * 16) ^ ((q & 7) << 4)));
    *(bf16x8*)&pg[(size_t)q * 512 + lane * 8] = v;
  }

  // ---- PV from LDS: wave = (q-half qh_) x (dk-half th_), no cross-wave reduce ----
  f32x4 pacc[2];
#pragma unroll
  for (int j = 0; j < 2; ++j)
#pragma unroll
    for (int q = 0; q < 4; ++q) pacc[j][q] = 0.f;
  const short* vb = Vt + (size_t)bh * 64 * 512 + (size_t)(th_ * 32) * 512;
  const int qr = qh_ * 16 + r16;
  const int rswz = (qr & 7) << 4;
  for (int kt = 0; kt < 512; kt += 32) {
    bf16x8 af = *(const bf16x8*)(plc + qr * 1024 + (((kt + g * 8) * 2) ^ rswz));
#pragma unroll
    for (int j = 0; j < 2; ++j) {
      bf16x8 bfr = *(const bf16x8*)&vb[(size_t)(j * 16 + r16) * 512 + kt + g * 8];
      pacc[j] = __builtin_amdgcn_mfma_f32_16x16x32_bf16(af, bfr, pacc[j], 0, 0, 0);
    }
  }
#pragma unroll
  for (int j = 0; j < 2; ++j) {
    int col = h * 64 + th_ * 32 + j * 16 + r16;
#pragma unroll
    for (int q = 0; q < 4; ++q)
      ctxb[(size_t)(b * 512 + q0 + qh_ * 16 + g * 4 + q) * 512 + col] = f2bf(pacc[j][q]);
  }
}

// ---------------- KL(avg_attn || uniform) per query row; one wave per row ----------------
template <int FIRST>
__global__ __launch_bounds__(256) void kl_kernel(const short* __restrict__ P,
                                                 float* __restrict__ assoc) {
  const int wid = threadIdx.x >> 6, lane = threadIdx.x & 63;
  const int row = blockIdx.x * 4 + wid;  // b*512 + q
  const int b = row >> 9, q = row & 511;
  const float prior = 1.0f / 512.0f + 1e-8f;
  float hs[8] = {0.f, 0.f, 0.f, 0.f, 0.f, 0.f, 0.f, 0.f};
#pragma unroll
  for (int h = 0; h < 8; ++h) {
    bf16x8 v = *(const bf16x8*)&P[(((size_t)(b * 8 + h)) * 512 + q) * 512 + lane * 8];
#pragma unroll
    for (int k = 0; k < 8; ++k) hs[k] += bf2f((unsigned short)v[k]);
  }
  float s = 0.f;
#pragma unroll
  for (int k = 0; k < 8; ++k) {
    float a = hs[k] * 0.125f + 1e-8f;
    s += a * __logf(a / prior);
  }
#pragma unroll
  for (int m = 32; m; m >>= 1) s += __shfl_xor(s, m, 64);
  if (lane == 0) assoc[row] = FIRST ? s : (assoc[row] + s);
}

// ---------------- layernorm: h = LN(h + res_bf16)*g + b; fp32 + bf16 out (vectorized) ----------------
__global__ __launch_bounds__(256) void ln_kernel(const float* __restrict__ hin,
                                                 const short* __restrict__ res,
                                                 const float* __restrict__ g,
                                                 const float* __restrict__ bta,
                                                 float* __restrict__ hout, short* __restrict__ hbf) {
  const int wid = threadIdx.x >> 6, lane = threadIdx.x & 63;
  const size_t row = (size_t)blockIdx.x * 4 + wid;
  const float* hp = hin + row * 512 + lane * 8;
  float4v a0 = *(const float4v*)hp;
  float4v a1 = *(const float4v*)(hp + 4);
  bf16x8 rv = *(const bf16x8*)(res + row * 512 + lane * 8);
  float v[8], s = 0.f, s2 = 0.f;
#pragma unroll
  for (int i = 0; i < 8; i++) {
    float base = (i < 4) ? a0[i] : a1[i - 4];
    v[i] = base + bf2f((unsigned short)rv[i]);
    s += v[i];
    s2 += v[i] * v[i];
  }
#pragma unroll
  for (int m = 32; m; m >>= 1) {
    s += __shfl_xor(s, m, 64);
    s2 += __shfl_xor(s2, m, 64);
  }
  float mu = s * (1.0f / 512.0f);
  float var = s2 * (1.0f / 512.0f) - mu * mu;
  float rs = rsqrtf(var + 1e-5f);
  const float* gp = g + lane * 8;
  const float* bp = bta + lane * 8;
  float4v o0, o1;
  bf16x8 ob;
#pragma unroll
  for (int i = 0; i < 8; i++) {
    float y = (v[i] - mu) * rs * gp[i] + bp[i];
    if (i < 4) o0[i] = y; else o1[i - 4] = y;
    ob[i] = f2bf(y);
  }
  float* op = hout + row * 512 + lane * 8;
  *(float4v*)op = o0;
  *(float4v*)(op + 4) = o1;
  *(bf16x8*)(hbf + row * 512 + lane * 8) = ob;
}

// ---------------- reconstruction via MFMA: out[4096,32] = h_bf @ WoutT^T + bout ----------------
__global__ __launch_bounds__(256) void recon_mfma(const short* __restrict__ hbf,
                                                  const short* __restrict__ WoutT,
                                                  const float* __restrict__ bout,
                                                  float* __restrict__ out) {
  const int wid = threadIdx.x >> 6, lane = threadIdx.x & 63;
  const int r16 = lane & 15, kg = (lane >> 4) * 8;
  const int wbase = blockIdx.x * 128 + wid * 32;

  f32x4 acc[2][2];
#pragma unroll
  for (int i = 0; i < 2; i++)
#pragma unroll
    for (int j = 0; j < 2; j++)
#pragma unroll
      for (int q = 0; q < 4; q++) acc[i][j][q] = 0.0f;

  for (int kt = 0; kt < 512; kt += 32) {
    bf16x8 af[2], bfr[2];
#pragma unroll
    for (int i = 0; i < 2; i++)
      af[i] = *(const bf16x8*)&hbf[(size_t)(wbase + i * 16 + r16) * 512 + kt + kg];
#pragma unroll
    for (int j = 0; j < 2; j++)
      bfr[j] = *(const bf16x8*)&WoutT[(size_t)(j * 16 + r16) * 512 + kt + kg];
#pragma unroll
    for (int i = 0; i < 2; i++)
#pragma unroll
      for (int j = 0; j < 2; j++)
        acc[i][j] = __builtin_amdgcn_mfma_f32_16x16x32_bf16(af[i], bfr[j], acc[i][j], 0, 0, 0);
  }

  const int rowg = (lane >> 4) * 4;
#pragma unroll
  for (int i = 0; i < 2; i++)
#pragma unroll
    for (int j = 0; j < 2; j++) {
      int col = j * 16 + r16;
#pragma unroll
      for (int q = 0; q < 4; q++)
        out[(size_t)(wbase + i * 16 + rowg + q) * 32 + col] = acc[i][j][q] + bout[col];
    }
}

// ---------------- score stage 2 + assoc output ----------------
__global__ __launch_bounds__(256) void score2_kernel(const short* __restrict__ s1,
                                                     const float* __restrict__ Ws2,
                                                     const float* __restrict__ bs2,
                                                     const float* __restrict__ assoc,
                                                     float* __restrict__ outScore,
                                                     float* __restrict__ outAssoc) {
  const int wid = threadIdx.x >> 6, lane = threadIdx.x & 63;
  const int row = blockIdx.x * 4 + wid;
  const short* rp = &s1[(size_t)row * 256 + lane * 4];
  float d = 0.f;
#pragma unroll
  for (int e = 0; e < 4; e++) d += bf2f((unsigned short)rp[e]) * Ws2[lane * 4 + e];
#pragma unroll
  for (int m = 32; m; m >>= 1) d += __shfl_xor(d, m, 64);
  if (lane == 0) {
    outScore[row] = 1.f / (1.f + __expf(-(d + bs2[0])));
    outAssoc[row] = assoc[row] * (1.0f / 6.0f);
  }
}

extern "C" void kernel_launch(void* const* d_in, const int* in_sizes, int n_in,
                              void* d_out, int out_size, void* d_ws, size_t ws_size,
                              hipStream_t stream) {
  const float* x    = (const float*)d_in[0];
  const float* W_in = (const float*)d_in[1];
  const float* b_in = (const float*)d_in[2];
  const float* pe   = (const float*)d_in[3];
  const float* Wq   = (const float*)d_in[4];
  const float* Wk   = (const float*)d_in[5];
  const float* Wv   = (const float*)d_in[6];
  const float* Wo   = (const float*)d_in[7];
  const float* bo   = (const float*)d_in[8];
  const float* W1   = (const float*)d_in[9];
  const float* b1   = (const float*)d_in[10];
  const float* W2   = (const float*)d_in[11];
  const float* b2   = (const float*)d_in[12];
  const float* ln1g = (const float*)d_in[13];
  const float* ln1b = (const float*)d_in[14];
  const float* ln2g = (const float*)d_in[15];
  const float* ln2b = (const float*)d_in[16];
  const float* Wout = (const float*)d_in[17];
  const float* bout = (const float*)d_in[18];
  const float* Ws1  = (const float*)d_in[19];
  const float* bs1  = (const float*)d_in[20];
  const float* Ws2  = (const float*)d_in[21];
  const float* bs2  = (const float*)d_in[22];

  char* p = (char*)d_ws;
  auto alloc = [&](size_t bytes) {
    void* r = (void*)p;
    p += (bytes + 255) & ~(size_t)255;
    return r;
  };
  float* h     = (float*)alloc((size_t)4096 * 512 * 4);
  short* h_bf  = (short*)alloc((size_t)4096 * 512 * 2);
  short* qh    = (short*)alloc((size_t)4096 * 1536 * 2);  // dense [sect*64+bh][t][64]
  short* aout  = (short*)alloc((size_t)4096 * 512 * 2);
  short* ctxb  = (short*)alloc((size_t)4096 * 512 * 2);
  short* ff1b  = (short*)alloc((size_t)4096 * 2048 * 2);
  short* ff2   = (short*)alloc((size_t)4096 * 512 * 2);
  float* assoc = (float*)alloc((size_t)4096 * 4);
  short* Pbuf  = (short*)alloc((size_t)64 * 512 * 512 * 2);
  short* Vt    = (short*)alloc((size_t)64 * 64 * 512 * 2);
  short* sc1   = (short*)alloc((size_t)4096 * 256 * 2);
  short* qkvt  = (short*)alloc((size_t)6 * 1536 * 512 * 2);
  short* wot   = (short*)alloc((size_t)6 * 512 * 512 * 2);
  short* w1t   = (short*)alloc((size_t)6 * 2048 * 512 * 2);
  short* w2t   = (short*)alloc((size_t)6 * 512 * 2048 * 2);
  short* ws1t  = (short*)alloc((size_t)256 * 512 * 2);
  short* woutT = (short*)alloc((size_t)32 * 512 * 2);

  // weight transpose+convert (per launch; graph-capture safe)
  transpose_qkv<<<dim3(16, 16, 18), 256, 0, stream>>>(Wq, Wk, Wv, qkvt);
  transpose_bf<<<dim3(16, 16, 6), 256, 0, stream>>>(Wo, wot, 512, 512, 262144, 262144);
  transpose_bf<<<dim3(64, 16, 6), 256, 0, stream>>>(W1, w1t, 512, 2048, 1048576, 1048576);
  transpose_bf<<<dim3(16, 64, 6), 256, 0, stream>>>(W2, w2t, 2048, 512, 1048576, 1048576);
  transpose_bf<<<dim3(8, 16, 1), 256, 0, stream>>>(Ws1, ws1t, 512, 256, 0, 0);
  transpose_bf<<<dim3(1, 16, 1), 256, 0, stream>>>(Wout, woutT, 512, 32, 0, 0);

  embed_kernel<<<8192, 256, 0, stream>>>(x, W_in, b_in, pe, h, h_bf);

  for (int l = 0; l < 6; ++l) {
    gemm_bt<5, 128, 128, 32><<<dim3(12, 32), 256, 0, stream>>>(
        h_bf, qkvt + (size_t)l * 786432, nullptr, qh, nullptr, 4096, 1536, 512);
    vt_kernel<<<dim3(16, 2, 64), 256, 0, stream>>>(qh, Vt);
    smpv_kernel<<<dim3(16, 64), 256, 0, stream>>>(qh, Vt, Pbuf, ctxb);
    if (l == 0)
      kl_kernel<1><<<1024, 256, 0, stream>>>(Pbuf, assoc);
    else
      kl_kernel<0><<<1024, 256, 0, stream>>>(Pbuf, assoc);
    gemm_bt<4, 64, 64, 32><<<dim3(8, 64), 256, 0, stream>>>(
        ctxb, wot + (size_t)l * 262144, nullptr, aout, bo + l * 512, 4096, 512, 512);
    ln_kernel<<<1024, 256, 0, stream>>>(h, aout, ln1g + l * 512, ln1b + l * 512, h, h_bf);
    gemm_bt<2, 128, 128, 32><<<dim3(16, 32), 256, 0, stream>>>(
        h_bf, w1t + (size_t)l * 1048576, nullptr, ff1b, b1 + l * 2048, 4096, 2048, 512);
    gemm_bt<4, 64, 64, 32><<<dim3(8, 64), 256, 0, stream>>>(
        ff1b, w2t + (size_t)l * 1048576, nullptr, ff2, b2 + l * 512, 4096, 512, 2048);
    ln_kernel<<<1024, 256, 0, stream>>>(h, ff2, ln2g + l * 512, ln2b + l * 512, h, h_bf);
  }

  float* out = (float*)d_out;
  recon_mfma<<<32, 256, 0, stream>>>(h_bf, woutT, bout, out);
  gemm_bt<2, 128, 128, 32><<<dim3(2, 32), 256, 0, stream>>>(h_bf, ws1t, nullptr, sc1, bs1,
                                                            4096, 256, 512);
  score2_kernel<<<1024, 256, 0, stream>>>(sc1, Ws2, bs2, assoc, out + 131072,
                                          out + 131072 + 4096);
}

// Round 10
// 801.271 us; speedup vs baseline: 1.2196x; 1.0792x over previous
//
#include <hip/hip_runtime.h>
#include <math.h>

typedef __attribute__((ext_vector_type(8))) short bf16x8;
typedef __attribute__((ext_vector_type(4))) float f32x4;

__device__ __forceinline__ short f2bf(float v) {
  union { float f; unsigned u; } x; x.f = v;
  unsigned r = x.u + 0x7fffu + ((x.u >> 16) & 1u);
  return (short)(r >> 16);
}

__device__ __forceinline__ float bf2f(unsigned short u) {
  union { unsigned u; float f; } x; x.u = ((unsigned)u) << 16;
  return x.f;
}

__device__ __forceinline__ void gld_lds16(const void* g, void* l) {
  __builtin_amdgcn_global_load_lds((const __attribute__((address_space(1))) void*)g,
                                   (__attribute__((address_space(3))) void*)l, 16, 0, 0);
}

// ---------------- mega prologue: embed + ALL weight transposes in one dispatch ----------------
// idx<8192: embed rows; then 32x32 fp32->bf16 transpose tiles for qkv/wo/w1/w2/ws1/wout.
__global__ __launch_bounds__(256) void prologue_kernel(
    const float* __restrict__ x, const float* __restrict__ W_in, const float* __restrict__ b_in,
    const float* __restrict__ pe, short* __restrict__ hbf,
    const float* __restrict__ Wq, const float* __restrict__ Wk, const float* __restrict__ Wv,
    const float* __restrict__ Wo, const float* __restrict__ W1, const float* __restrict__ W2,
    const float* __restrict__ Ws1, const float* __restrict__ Wout,
    short* __restrict__ qkvt, short* __restrict__ wot, short* __restrict__ w1t,
    short* __restrict__ w2t, short* __restrict__ ws1t, short* __restrict__ woutT) {
  __shared__ float t[32][33];
  const int tid = threadIdx.x;
  int idx = blockIdx.x;
  if (idx < 8192) {  // ---- embed: h_bf = bf16(x @ W_in + b_in + pe) ----
    int col = (idx & 1) * 256 + tid;
    int row = idx >> 1;
    int s = row & 511;
    float a = b_in[col] + pe[s * 512 + col];
    const float* xr = x + (size_t)row * 32;
#pragma unroll
    for (int k = 0; k < 32; k++) a += xr[k] * W_in[k * 512 + col];
    hbf[(size_t)row * 512 + col] = f2bf(a);
    return;
  }
  idx -= 8192;
  const float* src;
  short* dst;
  int R, C, cx, cy;
  if (idx < 4608) {  // qkv: 18 z x (16x16)
    int z = idx >> 8, rem = idx & 255;
    cx = rem & 15; cy = rem >> 4;
    int which = z / 6, l = z % 6;
    src = (which == 0 ? Wq : which == 1 ? Wk : Wv) + (size_t)l * 262144;
    dst = qkvt + (size_t)l * 786432 + (size_t)which * 262144;
    R = 512; C = 512;
  } else if (idx < 6144) {  // wo: 6 z x (16x16)
    int j = idx - 4608;
    int l = j >> 8, rem = j & 255;
    cx = rem & 15; cy = rem >> 4;
    src = Wo + (size_t)l * 262144; dst = wot + (size_t)l * 262144;
    R = 512; C = 512;
  } else if (idx < 12288) {  // w1: 6 z x (64x16)
    int j = idx - 6144;
    int l = j >> 10, rem = j & 1023;
    cx = rem & 63; cy = rem >> 6;
    src = W1 + (size_t)l * 1048576; dst = w1t + (size_t)l * 1048576;
    R = 512; C = 2048;
  } else if (idx < 18432) {  // w2: 6 z x (16x64)
    int j = idx - 12288;
    int l = j >> 10, rem = j & 1023;
    cx = rem & 15; cy = rem >> 4;
    src = W2 + (size_t)l * 1048576; dst = w2t + (size_t)l * 1048576;
    R = 2048; C = 512;
  } else if (idx < 18560) {  // ws1: (8x16)
    int j = idx - 18432;
    cx = j & 7; cy = j >> 3;
    src = Ws1; dst = ws1t; R = 512; C = 256;
  } else {  // wout: (1x16)
    int j = idx - 18560;
    cx = 0; cy = j;
    src = Wout; dst = woutT; R = 512; C = 32;
  }
  const int tx = tid & 31, ty = tid >> 5;
  const int c0 = cx * 32, r0 = cy * 32;
#pragma unroll
  for (int i = 0; i < 4; i++)
    t[ty + i * 8][tx] = src[(size_t)(r0 + ty + i * 8) * C + c0 + tx];
  __syncthreads();
#pragma unroll
  for (int i = 0; i < 4; i++)
    dst[(size_t)(c0 + ty + i * 8) * R + r0 + tx] = f2bf(t[tx][ty + i * 8]);
}

// ---------------- bf16 GEMM: A[M,K] x Bt[N,K]^T -> C[M,N] ----------------
// EPI: 2 bf16+bias+relu; 4 bf16+bias; 5 bf16 QKV->dense per-head layout
// BK=32 only: 64B LDS row stride = 2-way bank alias (free, m136); BK=64 was 32-way (r4).
template <int EPI, int BM, int BN, int BK>
__global__ __launch_bounds__(256) void gemm_bt(const short* __restrict__ A,
                                               const short* __restrict__ Bt,
                                               short* __restrict__ Cb,
                                               const float* __restrict__ bias,
                                               int M, int N, int K) {
  __shared__ short As[BM * BK];
  __shared__ short Bs[BN * BK];
  const int tid = threadIdx.x;
  const int wid = tid >> 6;
  const int lane = tid & 63;
  const int m0 = blockIdx.y * BM;
  const int n0 = blockIdx.x * BN;
  constexpr int WR = BM / 2, WC = BN / 2, FI = WR / 16, FJ = WC / 16, KK = BK / 32;
  const int wr = (wid >> 1) * WR;
  const int wc = (wid & 1) * WC;

  f32x4 acc[FI][FJ];
#pragma unroll
  for (int i = 0; i < FI; i++)
#pragma unroll
    for (int j = 0; j < FJ; j++)
#pragma unroll
      for (int q = 0; q < 4; q++) acc[i][j][q] = 0.0f;

  const short* aBase = A + (size_t)m0 * K;
  const short* bBase = Bt + (size_t)n0 * K;
  constexpr int RPC = 512 / BK;
  constexpr int CA = BM / RPC;
  constexpr int CT = (BM + BN) / RPC;
  const int rowL = lane / (64 / RPC);
  const int colE = (lane % (64 / RPC)) * 8;
  const int kg = (lane >> 4) * 8;
  const int r16 = lane & 15;

  for (int kt = 0; kt < K; kt += BK) {
    __syncthreads();
#pragma unroll
    for (int c = 0; c < CT / 4; ++c) {
      int s = c * 4 + wid;
      if (s < CA)
        gld_lds16(aBase + (size_t)(s * RPC + rowL) * K + kt + colE, As + s * 512);
      else
        gld_lds16(bBase + (size_t)((s - CA) * RPC + rowL) * K + kt + colE, Bs + (s - CA) * 512);
    }
    __syncthreads();
    bf16x8 af[FI][KK], bfr[FJ][KK];
#pragma unroll
    for (int i = 0; i < FI; i++)
#pragma unroll
      for (int kk = 0; kk < KK; kk++)
        af[i][kk] = *(const bf16x8*)&As[(wr + i * 16 + r16) * BK + kk * 32 + kg];
#pragma unroll
    for (int j = 0; j < FJ; j++)
#pragma unroll
      for (int kk = 0; kk < KK; kk++)
        bfr[j][kk] = *(const bf16x8*)&Bs[(wc + j * 16 + r16) * BK + kk * 32 + kg];
#pragma unroll
    for (int kk = 0; kk < KK; kk++)
#pragma unroll
      for (int i = 0; i < FI; i++)
#pragma unroll
        for (int j = 0; j < FJ; j++)
          acc[i][j] = __builtin_amdgcn_mfma_f32_16x16x32_bf16(af[i][kk], bfr[j][kk], acc[i][j], 0, 0, 0);
  }

  const int col16 = lane & 15;
  const int rowg = (lane >> 4) * 4;
#pragma unroll
  for (int i = 0; i < FI; i++) {
    int row = m0 + wr + i * 16 + rowg;
#pragma unroll
    for (int j = 0; j < FJ; j++) {
      int col = n0 + wc + j * 16 + col16;
      float bv = (EPI == 2 || EPI == 4) ? bias[col] : 0.0f;
#pragma unroll
      for (int q = 0; q < 4; q++) {
        float v = acc[i][j][q] + bv;
        if (EPI == 2) {
          v = fmaxf(v, 0.0f);
          Cb[(size_t)(row + q) * N + col] = f2bf(v);
        } else if (EPI == 5) {
          int rr = row + q;
          int sect = col >> 9, hh = (col >> 6) & 7, dk = col & 63;
          int bq = rr >> 9, tt = rr & 511;
          Cb[(((size_t)(sect * 64 + bq * 8 + hh)) * 512 + tt) * 64 + dk] = f2bf(v);
        } else {
          Cb[(size_t)(row + q) * N + col] = f2bf(v);
        }
      }
    }
  }
}

// ---------------- V transpose (dense layout): qh V-section -> Vt[bh][64 dk][512 t] ----------------
__global__ __launch_bounds__(256) void vt_kernel(const short* __restrict__ qh,
                                                 short* __restrict__ Vt) {
  __shared__ short t[32][34];
  const int bh = blockIdx.z;
  const int t0 = blockIdx.x * 32, d0 = blockIdx.y * 32;
  const int tx = threadIdx.x & 31, ty = threadIdx.x >> 5;
  const short* Vh = qh + (size_t)(128 + bh) * 512 * 64;
#pragma unroll
  for (int i = 0; i < 4; i++)
    t[ty + i * 8][tx] = Vh[(size_t)(t0 + ty + i * 8) * 64 + d0 + tx];
  __syncthreads();
#pragma unroll
  for (int i = 0; i < 4; i++)
    Vt[((size_t)bh * 64 + d0 + ty + i * 8) * 512 + t0 + tx] = t[tx][ty + i * 8];
}

// ---------------- fused scores+softmax+P(coalesced dump)+PV: per (bh, 32-query tile) ----------------
__global__ __launch_bounds__(256) void smpv_kernel(const short* __restrict__ qh,
                                                   const short* __restrict__ Vt,
                                                   short* __restrict__ P,
                                                   short* __restrict__ ctxb) {
  __shared__ short Pl[32 * 512];
  __shared__ float red0[2][2][16];
  __shared__ float red1[2][2][16];
  const int bh = blockIdx.y, b = bh >> 3, h = bh & 7;
  const int q0 = blockIdx.x * 32;
  const int tid = threadIdx.x;
  const int wid = tid >> 6, lane = tid & 63;
  const int r16 = lane & 15, g = lane >> 4;
  const int qh_ = wid & 1, th_ = wid >> 1;

  const short* Qh = qh + ((size_t)bh * 512) * 64;
  const short* Kh = qh + ((size_t)(64 + bh) * 512) * 64;

  const short* qp = Qh + (size_t)(q0 + qh_ * 16 + r16) * 64 + g * 8;
  const bf16x8 qa0 = *(const bf16x8*)qp;
  const bf16x8 qa1 = *(const bf16x8*)(qp + 32);

  f32x4 acc[16];
#pragma unroll
  for (int tt = 0; tt < 16; ++tt) {
    const short* kp = Kh + (size_t)(th_ * 256 + tt * 16 + r16) * 64 + g * 8;
    bf16x8 kb0 = *(const bf16x8*)kp;
    bf16x8 kb1 = *(const bf16x8*)(kp + 32);
    f32x4 c = {0.f, 0.f, 0.f, 0.f};
    c = __builtin_amdgcn_mfma_f32_16x16x32_bf16(qa0, kb0, c, 0, 0, 0);
    c = __builtin_amdgcn_mfma_f32_16x16x32_bf16(qa1, kb1, c, 0, 0, 0);
    acc[tt] = c;
  }

  float mx[4] = {-1e30f, -1e30f, -1e30f, -1e30f};
#pragma unroll
  for (int tt = 0; tt < 16; ++tt)
#pragma unroll
    for (int r = 0; r < 4; ++r) mx[r] = fmaxf(mx[r], acc[tt][r]);
#pragma unroll
  for (int r = 0; r < 4; ++r)
#pragma unroll
    for (int m = 8; m; m >>= 1) mx[r] = fmaxf(mx[r], __shfl_xor(mx[r], m, 16));
  if (r16 == 0) {
#pragma unroll
    for (int r = 0; r < 4; ++r) red0[th_][qh_][g * 4 + r] = mx[r];
  }
  __syncthreads();
#pragma unroll
  for (int r = 0; r < 4; ++r) {
    int q = g * 4 + r;
    mx[r] = fmaxf(red0[0][qh_][q], red0[1][qh_][q]);
  }
  float sum[4] = {0.f, 0.f, 0.f, 0.f};
#pragma unroll
  for (int tt = 0; tt < 16; ++tt)
#pragma unroll
    for (int r = 0; r < 4; ++r) {
      float e = __expf((acc[tt][r] - mx[r]) * 0.125f);
      acc[tt][r] = e;
      sum[r] += e;
    }
#pragma unroll
  for (int r = 0; r < 4; ++r)
#pragma unroll
    for (int m = 8; m; m >>= 1) sum[r] += __shfl_xor(sum[r], m, 16);
  if (r16 == 0) {
#pragma unroll
    for (int r = 0; r < 4; ++r) red1[th_][qh_][g * 4 + r] = sum[r];
  }
  __syncthreads();

  char* plc = (char*)Pl;
#pragma unroll
  for (int r = 0; r < 4; ++r) {
    int q = qh_ * 16 + g * 4 + r;
    float inv = 1.0f / (red1[0][qh_][g * 4 + r] + red1[1][qh_][g * 4 + r]);
    int swz = (q & 7) << 4;
#pragma unroll
    for (int tt = 0; tt < 16; ++tt)
      *(short*)(plc + q * 1024 + (((th_ * 256 + tt * 16 + r16) * 2) ^ swz)) =
          f2bf(acc[tt][r] * inv);
  }
  __syncthreads();

  short* pg = P + ((size_t)bh * 512 + q0) * 512;
#pragma unroll
  for (int rr = 0; rr < 8; ++rr) {
    int q = wid * 8 + rr;
    bf16x8 v = *(const bf16x8*)(plc + q * 1024 + ((lane * 16) ^ ((q & 7) << 4)));
    *(bf16x8*)&pg[(size_t)q * 512 + lane * 8] = v;
  }

  f32x4 pacc[2];
#pragma unroll
  for (int j = 0; j < 2; ++j)
#pragma unroll
    for (int q = 0; q < 4; ++q) pacc[j][q] = 0.f;
  const short* vb = Vt + (size_t)bh * 64 * 512 + (size_t)(th_ * 32) * 512;
  const int qr = qh_ * 16 + r16;
  const int rswz = (qr & 7) << 4;
  for (int kt = 0; kt < 512; kt += 32) {
    bf16x8 af = *(const bf16x8*)(plc + qr * 1024 + (((kt + g * 8) * 2) ^ rswz));
#pragma unroll
    for (int j = 0; j < 2; ++j) {
      bf16x8 bfr = *(const bf16x8*)&vb[(size_t)(j * 16 + r16) * 512 + kt + g * 8];
      pacc[j] = __builtin_amdgcn_mfma_f32_16x16x32_bf16(af, bfr, pacc[j], 0, 0, 0);
    }
  }
#pragma unroll
  for (int j = 0; j < 2; ++j) {
    int col = h * 64 + th_ * 32 + j * 16 + r16;
#pragma unroll
    for (int q = 0; q < 4; ++q)
      ctxb[(size_t)(b * 512 + q0 + qh_ * 16 + g * 4 + q) * 512 + col] = f2bf(pacc[j][q]);
  }
}

// ---------------- grid-union: Wo 64x64 GEMM (x<8) + KL head-sum (x>=8) ----------------
// Both depend only on smpv outputs; union overlaps kl's latency-bound P reads
// under the GEMM's MFMA work and saves a dispatch.
template <int FIRST>
__global__ __launch_bounds__(256) void wo_kl_kernel(const short* __restrict__ A,
                                                    const short* __restrict__ Bt,
                                                    const float* __restrict__ bias,
                                                    short* __restrict__ aout,
                                                    const short* __restrict__ P,
                                                    float* __restrict__ assoc) {
  __shared__ short As[64 * 32];
  __shared__ short Bs[64 * 32];
  const int tid = threadIdx.x;
  const int wid = tid >> 6, lane = tid & 63;
  if (blockIdx.x < 8) {
    // ---- Wo gemm: M=4096 N=512 K=512, BM=BN=64, BK=32 (copy of gemm_bt<4,64,64,32>) ----
    const int m0 = blockIdx.y * 64;
    const int n0 = blockIdx.x * 64;
    const int wr = (wid >> 1) * 32;
    const int wc = (wid & 1) * 32;
    f32x4 acc[2][2];
#pragma unroll
    for (int i = 0; i < 2; i++)
#pragma unroll
      for (int j = 0; j < 2; j++)
#pragma unroll
        for (int q = 0; q < 4; q++) acc[i][j][q] = 0.0f;
    const short* aBase = A + (size_t)m0 * 512;
    const short* bBase = Bt + (size_t)n0 * 512;
    const int rowL = lane >> 2;
    const int colE = (lane & 3) * 8;
    const int kg = (lane >> 4) * 8;
    const int r16 = lane & 15;
    for (int kt = 0; kt < 512; kt += 32) {
      __syncthreads();
#pragma unroll
      for (int c = 0; c < 2; ++c) {
        int s = c * 4 + wid;
        if (s < 4)
          gld_lds16(aBase + (size_t)(s * 16 + rowL) * 512 + kt + colE, As + s * 512);
        else
          gld_lds16(bBase + (size_t)((s - 4) * 16 + rowL) * 512 + kt + colE, Bs + (s - 4) * 512);
      }
      __syncthreads();
      bf16x8 af[2], bfr[2];
#pragma unroll
      for (int i = 0; i < 2; i++)
        af[i] = *(const bf16x8*)&As[(wr + i * 16 + r16) * 32 + kg];
#pragma unroll
      for (int j = 0; j < 2; j++)
        bfr[j] = *(const bf16x8*)&Bs[(wc + j * 16 + r16) * 32 + kg];
#pragma unroll
      for (int i = 0; i < 2; i++)
#pragma unroll
        for (int j = 0; j < 2; j++)
          acc[i][j] = __builtin_amdgcn_mfma_f32_16x16x32_bf16(af[i], bfr[j], acc[i][j], 0, 0, 0);
    }
    const int col16 = lane & 15;
    const int rowg = (lane >> 4) * 4;
#pragma unroll
    for (int i = 0; i < 2; i++) {
      int row = m0 + wr + i * 16 + rowg;
#pragma unroll
      for (int j = 0; j < 2; j++) {
        int col = n0 + wc + j * 16 + col16;
        float bv = bias[col];
#pragma unroll
        for (int q = 0; q < 4; q++)
          aout[(size_t)(row + q) * 512 + col] = f2bf(acc[i][j][q] + bv);
      }
    }
  } else {
    // ---- kl: one wave per query row ----
    const int kb = (blockIdx.x - 8) * 64 + blockIdx.y;
    const int row = kb * 4 + wid;
    const int b = row >> 9, q = row & 511;
    const float prior = 1.0f / 512.0f + 1e-8f;
    float hs[8] = {0.f, 0.f, 0.f, 0.f, 0.f, 0.f, 0.f, 0.f};
#pragma unroll
    for (int h = 0; h < 8; ++h) {
      bf16x8 v = *(const bf16x8*)&P[(((size_t)(b * 8 + h)) * 512 + q) * 512 + lane * 8];
#pragma unroll
      for (int k = 0; k < 8; ++k) hs[k] += bf2f((unsigned short)v[k]);
    }
    float s = 0.f;
#pragma unroll
    for (int k = 0; k < 8; ++k) {
      float a = hs[k] * 0.125f + 1e-8f;
      s += a * __logf(a / prior);
    }
#pragma unroll
    for (int m = 32; m; m >>= 1) s += __shfl_xor(s, m, 64);
    if (lane == 0) assoc[row] = FIRST ? s : (assoc[row] + s);
  }
}

// ---------------- layernorm in-place on bf16 residual stream: hbf = LN(hbf + res)*g + b ----------------
__global__ __launch_bounds__(256) void ln_kernel(const short* __restrict__ res,
                                                 const float* __restrict__ g,
                                                 const float* __restrict__ bta,
                                                 short* __restrict__ hbf) {
  const int wid = threadIdx.x >> 6, lane = threadIdx.x & 63;
  const size_t row = (size_t)blockIdx.x * 4 + wid;
  bf16x8 hv = *(const bf16x8*)&hbf[row * 512 + lane * 8];
  bf16x8 rv = *(const bf16x8*)&res[row * 512 + lane * 8];
  float v[8], s = 0.f, s2 = 0.f;
#pragma unroll
  for (int i = 0; i < 8; i++) {
    v[i] = bf2f((unsigned short)hv[i]) + bf2f((unsigned short)rv[i]);
    s += v[i];
    s2 += v[i] * v[i];
  }
#pragma unroll
  for (int m = 32; m; m >>= 1) {
    s += __shfl_xor(s, m, 64);
    s2 += __shfl_xor(s2, m, 64);
  }
  float mu = s * (1.0f / 512.0f);
  float var = s2 * (1.0f / 512.0f) - mu * mu;
  float rs = rsqrtf(var + 1e-5f);
  const float* gp = g + lane * 8;
  const float* bp = bta + lane * 8;
  bf16x8 ob;
#pragma unroll
  for (int i = 0; i < 8; i++) ob[i] = f2bf((v[i] - mu) * rs * gp[i] + bp[i]);
  *(bf16x8*)&hbf[row * 512 + lane * 8] = ob;
}

// ---------------- reconstruction via MFMA: out[4096,32] = h_bf @ WoutT^T + bout ----------------
__global__ __launch_bounds__(256) void recon_mfma(const short* __restrict__ hbf,
                                                  const short* __restrict__ WoutT,
                                                  const float* __restrict__ bout,
                                                  float* __restrict__ out) {
  const int wid = threadIdx.x >> 6, lane = threadIdx.x & 63;
  const int r16 = lane & 15, kg = (lane >> 4) * 8;
  const int wbase = blockIdx.x * 128 + wid * 32;

  f32x4 acc[2][2];
#pragma unroll
  for (int i = 0; i < 2; i++)
#pragma unroll
    for (int j = 0; j < 2; j++)
#pragma unroll
      for (int q = 0; q < 4; q++) acc[i][j][q] = 0.0f;

  for (int kt = 0; kt < 512; kt += 32) {
    bf16x8 af[2], bfr[2];
#pragma unroll
    for (int i = 0; i < 2; i++)
      af[i] = *(const bf16x8*)&hbf[(size_t)(wbase + i * 16 + r16) * 512 + kt + kg];
#pragma unroll
    for (int j = 0; j < 2; j++)
      bfr[j] = *(const bf16x8*)&WoutT[(size_t)(j * 16 + r16) * 512 + kt + kg];
#pragma unroll
    for (int i = 0; i < 2; i++)
#pragma unroll
      for (int j = 0; j < 2; j++)
        acc[i][j] = __builtin_amdgcn_mfma_f32_16x16x32_bf16(af[i], bfr[j], acc[i][j], 0, 0, 0);
  }

  const int rowg = (lane >> 4) * 4;
#pragma unroll
  for (int i = 0; i < 2; i++)
#pragma unroll
    for (int j = 0; j < 2; j++) {
      int col = j * 16 + r16;
#pragma unroll
      for (int q = 0; q < 4; q++)
        out[(size_t)(wbase + i * 16 + rowg + q) * 32 + col] = acc[i][j][q] + bout[col];
    }
}

// ---------------- score stage 2 + assoc output ----------------
__global__ __launch_bounds__(256) void score2_kernel(const short* __restrict__ s1,
                                                     const float* __restrict__ Ws2,
                                                     const float* __restrict__ bs2,
                                                     const float* __restrict__ assoc,
                                                     float* __restrict__ outScore,
                                                     float* __restrict__ outAssoc) {
  const int wid = threadIdx.x >> 6, lane = threadIdx.x & 63;
  const int row = blockIdx.x * 4 + wid;
  const short* rp = &s1[(size_t)row * 256 + lane * 4];
  float d = 0.f;
#pragma unroll
  for (int e = 0; e < 4; e++) d += bf2f((unsigned short)rp[e]) * Ws2[lane * 4 + e];
#pragma unroll
  for (int m = 32; m; m >>= 1) d += __shfl_xor(d, m, 64);
  if (lane == 0) {
    outScore[row] = 1.f / (1.f + __expf(-(d + bs2[0])));
    outAssoc[row] = assoc[row] * (1.0f / 6.0f);
  }
}

extern "C" void kernel_launch(void* const* d_in, const int* in_sizes, int n_in,
                              void* d_out, int out_size, void* d_ws, size_t ws_size,
                              hipStream_t stream) {
  const float* x    = (const float*)d_in[0];
  const float* W_in = (const float*)d_in[1];
  const float* b_in = (const float*)d_in[2];
  const float* pe   = (const float*)d_in[3];
  const float* Wq   = (const float*)d_in[4];
  const float* Wk   = (const float*)d_in[5];
  const float* Wv   = (const float*)d_in[6];
  const float* Wo   = (const float*)d_in[7];
  const float* bo   = (const float*)d_in[8];
  const float* W1   = (const float*)d_in[9];
  const float* b1   = (const float*)d_in[10];
  const float* W2   = (const float*)d_in[11];
  const float* b2   = (const float*)d_in[12];
  const float* ln1g = (const float*)d_in[13];
  const float* ln1b = (const float*)d_in[14];
  const float* ln2g = (const float*)d_in[15];
  const float* ln2b = (const float*)d_in[16];
  const float* Wout = (const float*)d_in[17];
  const float* bout = (const float*)d_in[18];
  const float* Ws1  = (const float*)d_in[19];
  const float* bs1  = (const float*)d_in[20];
  const float* Ws2  = (const float*)d_in[21];
  const float* bs2  = (const float*)d_in[22];

  char* p = (char*)d_ws;
  auto alloc = [&](size_t bytes) {
    void* r = (void*)p;
    p += (bytes + 255) & ~(size_t)255;
    return r;
  };
  short* h_bf  = (short*)alloc((size_t)4096 * 512 * 2);   // bf16 residual stream (in-place LN)
  short* qh    = (short*)alloc((size_t)4096 * 1536 * 2);  // dense [sect*64+bh][t][64]
  short* aout  = (short*)alloc((size_t)4096 * 512 * 2);
  short* ctxb  = (short*)alloc((size_t)4096 * 512 * 2);
  short* ff1b  = (short*)alloc((size_t)4096 * 2048 * 2);
  short* ff2   = (short*)alloc((size_t)4096 * 512 * 2);
  float* assoc = (float*)alloc((size_t)4096 * 4);
  short* Pbuf  = (short*)alloc((size_t)64 * 512 * 512 * 2);
  short* Vt    = (short*)alloc((size_t)64 * 64 * 512 * 2);
  short* sc1   = (short*)alloc((size_t)4096 * 256 * 2);
  short* qkvt  = (short*)alloc((size_t)6 * 1536 * 512 * 2);
  short* wot   = (short*)alloc((size_t)6 * 512 * 512 * 2);
  short* w1t   = (short*)alloc((size_t)6 * 2048 * 512 * 2);
  short* w2t   = (short*)alloc((size_t)6 * 512 * 2048 * 2);
  short* ws1t  = (short*)alloc((size_t)256 * 512 * 2);
  short* woutT = (short*)alloc((size_t)32 * 512 * 2);

  // one-dispatch prologue: embed + all weight transposes
  prologue_kernel<<<26768, 256, 0, stream>>>(x, W_in, b_in, pe, h_bf, Wq, Wk, Wv, Wo, W1, W2,
                                             Ws1, Wout, qkvt, wot, w1t, w2t, ws1t, woutT);

  for (int l = 0; l < 6; ++l) {
    gemm_bt<5, 128, 128, 32><<<dim3(12, 32), 256, 0, stream>>>(
        h_bf, qkvt + (size_t)l * 786432, qh, nullptr, 4096, 1536, 512);
    vt_kernel<<<dim3(16, 2, 64), 256, 0, stream>>>(qh, Vt);
    smpv_kernel<<<dim3(16, 64), 256, 0, stream>>>(qh, Vt, Pbuf, ctxb);
    if (l == 0)
      wo_kl_kernel<1><<<dim3(24, 64), 256, 0, stream>>>(ctxb, wot + (size_t)l * 262144,
                                                        bo + l * 512, aout, Pbuf, assoc);
    else
      wo_kl_kernel<0><<<dim3(24, 64), 256, 0, stream>>>(ctxb, wot + (size_t)l * 262144,
                                                        bo + l * 512, aout, Pbuf, assoc);
    ln_kernel<<<1024, 256, 0, stream>>>(aout, ln1g + l * 512, ln1b + l * 512, h_bf);
    gemm_bt<2, 128, 128, 32><<<dim3(16, 32), 256, 0, stream>>>(
        h_bf, w1t + (size_t)l * 1048576, ff1b, b1 + l * 2048, 4096, 2048, 512);
    gemm_bt<4, 64, 64, 32><<<dim3(8, 64), 256, 0, stream>>>(
        ff1b, w2t + (size_t)l * 1048576, ff2, b2 + l * 512, 4096, 512, 2048);
    ln_kernel<<<1024, 256, 0, stream>>>(ff2, ln2g + l * 512, ln2b + l * 512, h_bf);
  }

  float* out = (float*)d_out;
  recon_mfma<<<32, 256, 0, stream>>>(h_bf, woutT, bout, out);
  gemm_bt<2, 128, 128, 32><<<dim3(2, 32), 256, 0, stream>>>(h_bf, ws1t, sc1, bs1,
                                                            4096, 256, 512);
  score2_kernel<<<1024, 256, 0, stream>>>(sc1, Ws2, bs2, assoc, out + 131072,
                                          out + 131072 + 4096);
}

// Round 11
// 797.999 us; speedup vs baseline: 1.2246x; 1.0041x over previous
//
#include <hip/hip_runtime.h>
#include <math.h>

typedef __attribute__((ext_vector_type(8))) short bf16x8;
typedef __attribute__((ext_vector_type(4))) float f32x4;

__device__ __forceinline__ short f2bf(float v) {
  union { float f; unsigned u; } x; x.f = v;
  unsigned r = x.u + 0x7fffu + ((x.u >> 16) & 1u);
  return (short)(r >> 16);
}

__device__ __forceinline__ float bf2f(unsigned short u) {
  union { unsigned u; float f; } x; x.u = ((unsigned)u) << 16;
  return x.f;
}

__device__ __forceinline__ void gld_lds16(const void* g, void* l) {
  __builtin_amdgcn_global_load_lds((const __attribute__((address_space(1))) void*)g,
                                   (__attribute__((address_space(3))) void*)l, 16, 0, 0);
}

// ---------------- mega prologue: embed + ALL weight transposes in one dispatch ----------------
__global__ __launch_bounds__(256) void prologue_kernel(
    const float* __restrict__ x, const float* __restrict__ W_in, const float* __restrict__ b_in,
    const float* __restrict__ pe, short* __restrict__ hbf,
    const float* __restrict__ Wq, const float* __restrict__ Wk, const float* __restrict__ Wv,
    const float* __restrict__ Wo, const float* __restrict__ W1, const float* __restrict__ W2,
    const float* __restrict__ Ws1, const float* __restrict__ Wout,
    short* __restrict__ qkvt, short* __restrict__ wot, short* __restrict__ w1t,
    short* __restrict__ w2t, short* __restrict__ ws1t, short* __restrict__ woutT) {
  __shared__ float t[32][33];
  const int tid = threadIdx.x;
  int idx = blockIdx.x;
  if (idx < 8192) {  // ---- embed: h_bf = bf16(x @ W_in + b_in + pe) ----
    int col = (idx & 1) * 256 + tid;
    int row = idx >> 1;
    int s = row & 511;
    float a = b_in[col] + pe[s * 512 + col];
    const float* xr = x + (size_t)row * 32;
#pragma unroll
    for (int k = 0; k < 32; k++) a += xr[k] * W_in[k * 512 + col];
    hbf[(size_t)row * 512 + col] = f2bf(a);
    return;
  }
  idx -= 8192;
  const float* src;
  short* dst;
  int R, C, cx, cy;
  if (idx < 4608) {  // qkv: 18 z x (16x16)
    int z = idx >> 8, rem = idx & 255;
    cx = rem & 15; cy = rem >> 4;
    int which = z / 6, l = z % 6;
    src = (which == 0 ? Wq : which == 1 ? Wk : Wv) + (size_t)l * 262144;
    dst = qkvt + (size_t)l * 786432 + (size_t)which * 262144;
    R = 512; C = 512;
  } else if (idx < 6144) {  // wo: 6 z x (16x16)
    int j = idx - 4608;
    int l = j >> 8, rem = j & 255;
    cx = rem & 15; cy = rem >> 4;
    src = Wo + (size_t)l * 262144; dst = wot + (size_t)l * 262144;
    R = 512; C = 512;
  } else if (idx < 12288) {  // w1: 6 z x (64x16)
    int j = idx - 6144;
    int l = j >> 10, rem = j & 1023;
    cx = rem & 63; cy = rem >> 6;
    src = W1 + (size_t)l * 1048576; dst = w1t + (size_t)l * 1048576;
    R = 512; C = 2048;
  } else if (idx < 18432) {  // w2: 6 z x (16x64)
    int j = idx - 12288;
    int l = j >> 10, rem = j & 1023;
    cx = rem & 15; cy = rem >> 4;
    src = W2 + (size_t)l * 1048576; dst = w2t + (size_t)l * 1048576;
    R = 2048; C = 512;
  } else if (idx < 18560) {  // ws1: (8x16)
    int j = idx - 18432;
    cx = j & 7; cy = j >> 3;
    src = Ws1; dst = ws1t; R = 512; C = 256;
  } else {  // wout: (1x16)
    int j = idx - 18560;
    cx = 0; cy = j;
    src = Wout; dst = woutT; R = 512; C = 32;
  }
  const int tx = tid & 31, ty = tid >> 5;
  const int c0 = cx * 32, r0 = cy * 32;
#pragma unroll
  for (int i = 0; i < 4; i++)
    t[ty + i * 8][tx] = src[(size_t)(r0 + ty + i * 8) * C + c0 + tx];
  __syncthreads();
#pragma unroll
  for (int i = 0; i < 4; i++)
    dst[(size_t)(c0 + ty + i * 8) * R + r0 + tx] = f2bf(t[tx][ty + i * 8]);
}

// ---------------- bf16 GEMM: A[M,K] x Bt[N,K]^T -> C[M,N] ----------------
// EPI: 2 bf16+bias+relu; 4 bf16+bias; 5 bf16 QKV->dense per-head layout
// BK=32 only: 64B LDS row stride = 2-way bank alias (free, m136); BK=64 was 32-way (r4).
template <int EPI, int BM, int BN, int BK>
__global__ __launch_bounds__(256) void gemm_bt(const short* __restrict__ A,
                                               const short* __restrict__ Bt,
                                               short* __restrict__ Cb,
                                               const float* __restrict__ bias,
                                               int M, int N, int K) {
  __shared__ short As[BM * BK];
  __shared__ short Bs[BN * BK];
  const int tid = threadIdx.x;
  const int wid = tid >> 6;
  const int lane = tid & 63;
  const int m0 = blockIdx.y * BM;
  const int n0 = blockIdx.x * BN;
  constexpr int WR = BM / 2, WC = BN / 2, FI = WR / 16, FJ = WC / 16, KK = BK / 32;
  const int wr = (wid >> 1) * WR;
  const int wc = (wid & 1) * WC;

  f32x4 acc[FI][FJ];
#pragma unroll
  for (int i = 0; i < FI; i++)
#pragma unroll
    for (int j = 0; j < FJ; j++)
#pragma unroll
      for (int q = 0; q < 4; q++) acc[i][j][q] = 0.0f;

  const short* aBase = A + (size_t)m0 * K;
  const short* bBase = Bt + (size_t)n0 * K;
  constexpr int RPC = 512 / BK;
  constexpr int CA = BM / RPC;
  constexpr int CT = (BM + BN) / RPC;
  const int rowL = lane / (64 / RPC);
  const int colE = (lane % (64 / RPC)) * 8;
  const int kg = (lane >> 4) * 8;
  const int r16 = lane & 15;

  for (int kt = 0; kt < K; kt += BK) {
    __syncthreads();
#pragma unroll
    for (int c = 0; c < CT / 4; ++c) {
      int s = c * 4 + wid;
      if (s < CA)
        gld_lds16(aBase + (size_t)(s * RPC + rowL) * K + kt + colE, As + s * 512);
      else
        gld_lds16(bBase + (size_t)((s - CA) * RPC + rowL) * K + kt + colE, Bs + (s - CA) * 512);
    }
    __syncthreads();
    bf16x8 af[FI][KK], bfr[FJ][KK];
#pragma unroll
    for (int i = 0; i < FI; i++)
#pragma unroll
      for (int kk = 0; kk < KK; kk++)
        af[i][kk] = *(const bf16x8*)&As[(wr + i * 16 + r16) * BK + kk * 32 + kg];
#pragma unroll
    for (int j = 0; j < FJ; j++)
#pragma unroll
      for (int kk = 0; kk < KK; kk++)
        bfr[j][kk] = *(const bf16x8*)&Bs[(wc + j * 16 + r16) * BK + kk * 32 + kg];
#pragma unroll
    for (int kk = 0; kk < KK; kk++)
#pragma unroll
      for (int i = 0; i < FI; i++)
#pragma unroll
        for (int j = 0; j < FJ; j++)
          acc[i][j] = __builtin_amdgcn_mfma_f32_16x16x32_bf16(af[i][kk], bfr[j][kk], acc[i][j], 0, 0, 0);
  }

  const int col16 = lane & 15;
  const int rowg = (lane >> 4) * 4;
#pragma unroll
  for (int i = 0; i < FI; i++) {
    int row = m0 + wr + i * 16 + rowg;
#pragma unroll
    for (int j = 0; j < FJ; j++) {
      int col = n0 + wc + j * 16 + col16;
      float bv = (EPI == 2 || EPI == 4) ? bias[col] : 0.0f;
#pragma unroll
      for (int q = 0; q < 4; q++) {
        float v = acc[i][j][q] + bv;
        if (EPI == 2) {
          v = fmaxf(v, 0.0f);
          Cb[(size_t)(row + q) * N + col] = f2bf(v);
        } else if (EPI == 5) {
          int rr = row + q;
          int sect = col >> 9, hh = (col >> 6) & 7, dk = col & 63;
          int bq = rr >> 9, tt = rr & 511;
          Cb[(((size_t)(sect * 64 + bq * 8 + hh)) * 512 + tt) * 64 + dk] = f2bf(v);
        } else {
          Cb[(size_t)(row + q) * N + col] = f2bf(v);
        }
      }
    }
  }
}

// ---------------- V transpose (dense layout): qh V-section -> Vt[bh][64 dk][512 t] ----------------
__global__ __launch_bounds__(256) void vt_kernel(const short* __restrict__ qh,
                                                 short* __restrict__ Vt) {
  __shared__ short t[32][34];
  const int bh = blockIdx.z;
  const int t0 = blockIdx.x * 32, d0 = blockIdx.y * 32;
  const int tx = threadIdx.x & 31, ty = threadIdx.x >> 5;
  const short* Vh = qh + (size_t)(128 + bh) * 512 * 64;
#pragma unroll
  for (int i = 0; i < 4; i++)
    t[ty + i * 8][tx] = Vh[(size_t)(t0 + ty + i * 8) * 64 + d0 + tx];
  __syncthreads();
#pragma unroll
  for (int i = 0; i < 4; i++)
    Vt[((size_t)bh * 64 + d0 + ty + i * 8) * 512 + t0 + tx] = t[tx][ty + i * 8];
}

// ---------------- fused scores+softmax+P dump+PV: per (bh, 16-query tile) ----------------
// r10 smpv was latency-bound (Occ 17.7%, 4 blk/CU LDS-capped). 16q tile: LDS 17KB ->
// 8 blk/CU LDS-ceiling, grid 2048; waves split t 4-ways in QK^T, dk 4-ways in PV.
__global__ __launch_bounds__(256) void smpv_kernel(const short* __restrict__ qh,
                                                   const short* __restrict__ Vt,
                                                   short* __restrict__ P,
                                                   short* __restrict__ ctxb) {
  __shared__ short Pl[16 * 512];  // 16KB, [q][t] bf16, swizzled byte^=(q&7)<<4
  __shared__ float red0[4][16];
  __shared__ float red1[4][16];
  const int bh = blockIdx.y, b = bh >> 3, h = bh & 7;
  const int q0 = blockIdx.x * 16;
  const int tid = threadIdx.x;
  const int wid = tid >> 6, lane = tid & 63;
  const int r16 = lane & 15, g = lane >> 4;

  const short* Qh = qh + ((size_t)bh * 512) * 64;
  const short* Kh = qh + ((size_t)(64 + bh) * 512) * 64;

  // ---- QK^T: rows q0+r16(wave-shared A), cols t = wid*128 + tt*16 + r16 ----
  const short* qp = Qh + (size_t)(q0 + r16) * 64 + g * 8;
  const bf16x8 qa0 = *(const bf16x8*)qp;
  const bf16x8 qa1 = *(const bf16x8*)(qp + 32);

  f32x4 acc[8];
#pragma unroll
  for (int tt = 0; tt < 8; ++tt) {
    const short* kp = Kh + (size_t)(wid * 128 + tt * 16 + r16) * 64 + g * 8;
    bf16x8 kb0 = *(const bf16x8*)kp;
    bf16x8 kb1 = *(const bf16x8*)(kp + 32);
    f32x4 c = {0.f, 0.f, 0.f, 0.f};
    c = __builtin_amdgcn_mfma_f32_16x16x32_bf16(qa0, kb0, c, 0, 0, 0);
    c = __builtin_amdgcn_mfma_f32_16x16x32_bf16(qa1, kb1, c, 0, 0, 0);
    acc[tt] = c;
  }

  // ---- softmax: 16-lane reduce within t-quarter, then 4-way cross-wave via LDS ----
  float mx[4] = {-1e30f, -1e30f, -1e30f, -1e30f};
#pragma unroll
  for (int tt = 0; tt < 8; ++tt)
#pragma unroll
    for (int r = 0; r < 4; ++r) mx[r] = fmaxf(mx[r], acc[tt][r]);
#pragma unroll
  for (int r = 0; r < 4; ++r)
#pragma unroll
    for (int m = 8; m; m >>= 1) mx[r] = fmaxf(mx[r], __shfl_xor(mx[r], m, 16));
  if (r16 == 0) {
#pragma unroll
    for (int r = 0; r < 4; ++r) red0[wid][g * 4 + r] = mx[r];
  }
  __syncthreads();
#pragma unroll
  for (int r = 0; r < 4; ++r) {
    int q = g * 4 + r;
    mx[r] = fmaxf(fmaxf(red0[0][q], red0[1][q]), fmaxf(red0[2][q], red0[3][q]));
  }
  float sum[4] = {0.f, 0.f, 0.f, 0.f};
#pragma unroll
  for (int tt = 0; tt < 8; ++tt)
#pragma unroll
    for (int r = 0; r < 4; ++r) {
      float e = __expf((acc[tt][r] - mx[r]) * 0.125f);
      acc[tt][r] = e;
      sum[r] += e;
    }
#pragma unroll
  for (int r = 0; r < 4; ++r)
#pragma unroll
    for (int m = 8; m; m >>= 1) sum[r] += __shfl_xor(sum[r], m, 16);
  if (r16 == 0) {
#pragma unroll
    for (int r = 0; r < 4; ++r) red1[wid][g * 4 + r] = sum[r];
  }
  __syncthreads();

  // ---- P -> swizzled LDS strip ----
  char* plc = (char*)Pl;
#pragma unroll
  for (int r = 0; r < 4; ++r) {
    int q = g * 4 + r;
    float inv = 1.0f / (red1[0][q] + red1[1][q] + red1[2][q] + red1[3][q]);
    int swz = (q & 7) << 4;
#pragma unroll
    for (int tt = 0; tt < 8; ++tt)
      *(short*)(plc + q * 1024 + (((wid * 128 + tt * 16 + r16) * 2) ^ swz)) =
          f2bf(acc[tt][r] * inv);
  }
  __syncthreads();

  // ---- coalesced P dump to global (stores overlap following MFMA) ----
  short* pg = P + ((size_t)bh * 512 + q0) * 512;
#pragma unroll
  for (int k = 0; k < 4; ++k) {
    int c = k * 256 + tid;  // 16B chunk id, 1024 total
    int q = c >> 6;
    int tB = (c & 63) * 16;
    bf16x8 v = *(const bf16x8*)(plc + q * 1024 + (tB ^ ((q & 7) << 4)));
    *(bf16x8*)&pg[(size_t)q * 512 + (c & 63) * 8] = v;
  }

  // ---- PV from LDS: wave owns 16-wide dk slice (no cross-wave reduce) ----
  f32x4 pacc = {0.f, 0.f, 0.f, 0.f};
  const short* vb = Vt + (size_t)bh * 64 * 512 + (size_t)(wid * 16) * 512;
  const int rswz = (r16 & 7) << 4;
  for (int kt = 0; kt < 512; kt += 32) {
    bf16x8 af = *(const bf16x8*)(plc + r16 * 1024 + (((kt + g * 8) * 2) ^ rswz));
    bf16x8 bfr = *(const bf16x8*)&vb[(size_t)r16 * 512 + kt + g * 8];
    pacc = __builtin_amdgcn_mfma_f32_16x16x32_bf16(af, bfr, pacc, 0, 0, 0);
  }
  const int col = h * 64 + wid * 16 + r16;
#pragma unroll
  for (int q = 0; q < 4; ++q)
    ctxb[(size_t)(b * 512 + q0 + g * 4 + q) * 512 + col] = f2bf(pacc[q]);
}

// ---------------- grid-union: Wo 64x64 GEMM (x<8) + KL head-sum (x>=8) ----------------
template <int FIRST>
__global__ __launch_bounds__(256) void wo_kl_kernel(const short* __restrict__ A,
                                                    const short* __restrict__ Bt,
                                                    const float* __restrict__ bias,
                                                    short* __restrict__ aout,
                                                    const short* __restrict__ P,
                                                    float* __restrict__ assoc) {
  __shared__ short As[64 * 32];
  __shared__ short Bs[64 * 32];
  const int tid = threadIdx.x;
  const int wid = tid >> 6, lane = tid & 63;
  if (blockIdx.x < 8) {
    const int m0 = blockIdx.y * 64;
    const int n0 = blockIdx.x * 64;
    const int wr = (wid >> 1) * 32;
    const int wc = (wid & 1) * 32;
    f32x4 acc[2][2];
#pragma unroll
    for (int i = 0; i < 2; i++)
#pragma unroll
      for (int j = 0; j < 2; j++)
#pragma unroll
        for (int q = 0; q < 4; q++) acc[i][j][q] = 0.0f;
    const short* aBase = A + (size_t)m0 * 512;
    const short* bBase = Bt + (size_t)n0 * 512;
    const int rowL = lane >> 2;
    const int colE = (lane & 3) * 8;
    const int kg = (lane >> 4) * 8;
    const int r16 = lane & 15;
    for (int kt = 0; kt < 512; kt += 32) {
      __syncthreads();
#pragma unroll
      for (int c = 0; c < 2; ++c) {
        int s = c * 4 + wid;
        if (s < 4)
          gld_lds16(aBase + (size_t)(s * 16 + rowL) * 512 + kt + colE, As + s * 512);
        else
          gld_lds16(bBase + (size_t)((s - 4) * 16 + rowL) * 512 + kt + colE, Bs + (s - 4) * 512);
      }
      __syncthreads();
      bf16x8 af[2], bfr[2];
#pragma unroll
      for (int i = 0; i < 2; i++)
        af[i] = *(const bf16x8*)&As[(wr + i * 16 + r16) * 32 + kg];
#pragma unroll
      for (int j = 0; j < 2; j++)
        bfr[j] = *(const bf16x8*)&Bs[(wc + j * 16 + r16) * 32 + kg];
#pragma unroll
      for (int i = 0; i < 2; i++)
#pragma unroll
        for (int j = 0; j < 2; j++)
          acc[i][j] = __builtin_amdgcn_mfma_f32_16x16x32_bf16(af[i], bfr[j], acc[i][j], 0, 0, 0);
    }
    const int col16 = lane & 15;
    const int rowg = (lane >> 4) * 4;
#pragma unroll
    for (int i = 0; i < 2; i++) {
      int row = m0 + wr + i * 16 + rowg;
#pragma unroll
      for (int j = 0; j < 2; j++) {
        int col = n0 + wc + j * 16 + col16;
        float bv = bias[col];
#pragma unroll
        for (int q = 0; q < 4; q++)
          aout[(size_t)(row + q) * 512 + col] = f2bf(acc[i][j][q] + bv);
      }
    }
  } else {
    const int kb = (blockIdx.x - 8) * 64 + blockIdx.y;
    const int row = kb * 4 + wid;
    const int b = row >> 9, q = row & 511;
    const float prior = 1.0f / 512.0f + 1e-8f;
    float hs[8] = {0.f, 0.f, 0.f, 0.f, 0.f, 0.f, 0.f, 0.f};
#pragma unroll
    for (int h = 0; h < 8; ++h) {
      bf16x8 v = *(const bf16x8*)&P[(((size_t)(b * 8 + h)) * 512 + q) * 512 + lane * 8];
#pragma unroll
      for (int k = 0; k < 8; ++k) hs[k] += bf2f((unsigned short)v[k]);
    }
    float s = 0.f;
#pragma unroll
    for (int k = 0; k < 8; ++k) {
      float a = hs[k] * 0.125f + 1e-8f;
      s += a * __logf(a / prior);
    }
#pragma unroll
    for (int m = 32; m; m >>= 1) s += __shfl_xor(s, m, 64);
    if (lane == 0) assoc[row] = FIRST ? s : (assoc[row] + s);
  }
}

// ---------------- layernorm in-place on bf16 residual stream ----------------
__global__ __launch_bounds__(256) void ln_kernel(const short* __restrict__ res,
                                                 const float* __restrict__ g,
                                                 const float* __restrict__ bta,
                                                 short* __restrict__ hbf) {
  const int wid = threadIdx.x >> 6, lane = threadIdx.x & 63;
  const size_t row = (size_t)blockIdx.x * 4 + wid;
  bf16x8 hv = *(const bf16x8*)&hbf[row * 512 + lane * 8];
  bf16x8 rv = *(const bf16x8*)&res[row * 512 + lane * 8];
  float v[8], s = 0.f, s2 = 0.f;
#pragma unroll
  for (int i = 0; i < 8; i++) {
    v[i] = bf2f((unsigned short)hv[i]) + bf2f((unsigned short)rv[i]);
    s += v[i];
    s2 += v[i] * v[i];
  }
#pragma unroll
  for (int m = 32; m; m >>= 1) {
    s += __shfl_xor(s, m, 64);
    s2 += __shfl_xor(s2, m, 64);
  }
  float mu = s * (1.0f / 512.0f);
  float var = s2 * (1.0f / 512.0f) - mu * mu;
  float rs = rsqrtf(var + 1e-5f);
  const float* gp = g + lane * 8;
  const float* bp = bta + lane * 8;
  bf16x8 ob;
#pragma unroll
  for (int i = 0; i < 8; i++) ob[i] = f2bf((v[i] - mu) * rs * gp[i] + bp[i]);
  *(bf16x8*)&hbf[row * 512 + lane * 8] = ob;
}

// ---------------- reconstruction via MFMA: out[4096,32] = h_bf @ WoutT^T + bout ----------------
__global__ __launch_bounds__(256) void recon_mfma(const short* __restrict__ hbf,
                                                  const short* __restrict__ WoutT,
                                                  const float* __restrict__ bout,
                                                  float* __restrict__ out) {
  const int wid = threadIdx.x >> 6, lane = threadIdx.x & 63;
  const int r16 = lane & 15, kg = (lane >> 4) * 8;
  const int wbase = blockIdx.x * 128 + wid * 32;

  f32x4 acc[2][2];
#pragma unroll
  for (int i = 0; i < 2; i++)
#pragma unroll
    for (int j = 0; j < 2; j++)
#pragma unroll
      for (int q = 0; q < 4; q++) acc[i][j][q] = 0.0f;

  for (int kt = 0; kt < 512; kt += 32) {
    bf16x8 af[2], bfr[2];
#pragma unroll
    for (int i = 0; i < 2; i++)
      af[i] = *(const bf16x8*)&hbf[(size_t)(wbase + i * 16 + r16) * 512 + kt + kg];
#pragma unroll
    for (int j = 0; j < 2; j++)
      bfr[j] = *(const bf16x8*)&WoutT[(size_t)(j * 16 + r16) * 512 + kt + kg];
#pragma unroll
    for (int i = 0; i < 2; i++)
#pragma unroll
      for (int j = 0; j < 2; j++)
        acc[i][j] = __builtin_amdgcn_mfma_f32_16x16x32_bf16(af[i], bfr[j], acc[i][j], 0, 0, 0);
  }

  const int rowg = (lane >> 4) * 4;
#pragma unroll
  for (int i = 0; i < 2; i++)
#pragma unroll
    for (int j = 0; j < 2; j++) {
      int col = j * 16 + r16;
#pragma unroll
      for (int q = 0; q < 4; q++)
        out[(size_t)(wbase + i * 16 + rowg + q) * 32 + col] = acc[i][j][q] + bout[col];
    }
}

// ---------------- score stage 2 + assoc output ----------------
__global__ __launch_bounds__(256) void score2_kernel(const short* __restrict__ s1,
                                                     const float* __restrict__ Ws2,
                                                     const float* __restrict__ bs2,
                                                     const float* __restrict__ assoc,
                                                     float* __restrict__ outScore,
                                                     float* __restrict__ outAssoc) {
  const int wid = threadIdx.x >> 6, lane = threadIdx.x & 63;
  const int row = blockIdx.x * 4 + wid;
  const short* rp = &s1[(size_t)row * 256 + lane * 4];
  float d = 0.f;
#pragma unroll
  for (int e = 0; e < 4; e++) d += bf2f((unsigned short)rp[e]) * Ws2[lane * 4 + e];
#pragma unroll
  for (int m = 32; m; m >>= 1) d += __shfl_xor(d, m, 64);
  if (lane == 0) {
    outScore[row] = 1.f / (1.f + __expf(-(d + bs2[0])));
    outAssoc[row] = assoc[row] * (1.0f / 6.0f);
  }
}

extern "C" void kernel_launch(void* const* d_in, const int* in_sizes, int n_in,
                              void* d_out, int out_size, void* d_ws, size_t ws_size,
                              hipStream_t stream) {
  const float* x    = (const float*)d_in[0];
  const float* W_in = (const float*)d_in[1];
  const float* b_in = (const float*)d_in[2];
  const float* pe   = (const float*)d_in[3];
  const float* Wq   = (const float*)d_in[4];
  const float* Wk   = (const float*)d_in[5];
  const float* Wv   = (const float*)d_in[6];
  const float* Wo   = (const float*)d_in[7];
  const float* bo   = (const float*)d_in[8];
  const float* W1   = (const float*)d_in[9];
  const float* b1   = (const float*)d_in[10];
  const float* W2   = (const float*)d_in[11];
  const float* b2   = (const float*)d_in[12];
  const float* ln1g = (const float*)d_in[13];
  const float* ln1b = (const float*)d_in[14];
  const float* ln2g = (const float*)d_in[15];
  const float* ln2b = (const float*)d_in[16];
  const float* Wout = (const float*)d_in[17];
  const float* bout = (const float*)d_in[18];
  const float* Ws1  = (const float*)d_in[19];
  const float* bs1  = (const float*)d_in[20];
  const float* Ws2  = (const float*)d_in[21];
  const float* bs2  = (const float*)d_in[22];

  char* p = (char*)d_ws;
  auto alloc = [&](size_t bytes) {
    void* r = (void*)p;
    p += (bytes + 255) & ~(size_t)255;
    return r;
  };
  short* h_bf  = (short*)alloc((size_t)4096 * 512 * 2);
  short* qh    = (short*)alloc((size_t)4096 * 1536 * 2);
  short* aout  = (short*)alloc((size_t)4096 * 512 * 2);
  short* ctxb  = (short*)alloc((size_t)4096 * 512 * 2);
  short* ff1b  = (short*)alloc((size_t)4096 * 2048 * 2);
  short* ff2   = (short*)alloc((size_t)4096 * 512 * 2);
  float* assoc = (float*)alloc((size_t)4096 * 4);
  short* Pbuf  = (short*)alloc((size_t)64 * 512 * 512 * 2);
  short* Vt    = (short*)alloc((size_t)64 * 64 * 512 * 2);
  short* sc1   = (short*)alloc((size_t)4096 * 256 * 2);
  short* qkvt  = (short*)alloc((size_t)6 * 1536 * 512 * 2);
  short* wot   = (short*)alloc((size_t)6 * 512 * 512 * 2);
  short* w1t   = (short*)alloc((size_t)6 * 2048 * 512 * 2);
  short* w2t   = (short*)alloc((size_t)6 * 512 * 2048 * 2);
  short* ws1t  = (short*)alloc((size_t)256 * 512 * 2);
  short* woutT = (short*)alloc((size_t)32 * 512 * 2);

  prologue_kernel<<<26768, 256, 0, stream>>>(x, W_in, b_in, pe, h_bf, Wq, Wk, Wv, Wo, W1, W2,
                                             Ws1, Wout, qkvt, wot, w1t, w2t, ws1t, woutT);

  for (int l = 0; l < 6; ++l) {
    gemm_bt<5, 128, 128, 32><<<dim3(12, 32), 256, 0, stream>>>(
        h_bf, qkvt + (size_t)l * 786432, qh, nullptr, 4096, 1536, 512);
    vt_kernel<<<dim3(16, 2, 64), 256, 0, stream>>>(qh, Vt);
    smpv_kernel<<<dim3(32, 64), 256, 0, stream>>>(qh, Vt, Pbuf, ctxb);
    if (l == 0)
      wo_kl_kernel<1><<<dim3(24, 64), 256, 0, stream>>>(ctxb, wot + (size_t)l * 262144,
                                                        bo + l * 512, aout, Pbuf, assoc);
    else
      wo_kl_kernel<0><<<dim3(24, 64), 256, 0, stream>>>(ctxb, wot + (size_t)l * 262144,
                                                        bo + l * 512, aout, Pbuf, assoc);
    ln_kernel<<<1024, 256, 0, stream>>>(aout, ln1g + l * 512, ln1b + l * 512, h_bf);
    gemm_bt<2, 128, 128, 32><<<dim3(16, 32), 256, 0, stream>>>(
        h_bf, w1t + (size_t)l * 1048576, ff1b, b1 + l * 2048, 4096, 2048, 512);
    gemm_bt<4, 64, 64, 32><<<dim3(8, 64), 256, 0, stream>>>(
        ff1b, w2t + (size_t)l * 1048576, ff2, b2 + l * 512, 4096, 512, 2048);
    ln_kernel<<<1024, 256, 0, stream>>>(ff2, ln2g + l * 512, ln2b + l * 512, h_bf);
  }

  float* out = (float*)d_out;
  recon_mfma<<<32, 256, 0, stream>>>(h_bf, woutT, bout, out);
  gemm_bt<2, 128, 128, 32><<<dim3(2, 32), 256, 0, stream>>>(h_bf, ws1t, sc1, bs1,
                                                            4096, 256, 512);
  score2_kernel<<<1024, 256, 0, stream>>>(sc1, Ws2, bs2, assoc, out + 131072,
                                          out + 131072 + 4096);
}